// Round 10
// baseline (393.760 us; speedup 1.0000x reference)
//
#include <hip/hip_runtime.h>
#include <hip/hip_bf16.h>
#include <string.h>

// PerformerAttention: out = (relu(xWq^T+bq) @ [relu(xWk^T+bk)^T @ (xWv^T+bv)]_per-head) Wo^T + bo
// B=4 S=8192 E=768 H=12 Dh=64.
// Round 10: gemm3 — counted-vmcnt deep pipeline. BK=32, 3 LDS slots (48 KB, 3 blk/CU),
// staging 2 K-tiles ahead, ONE raw s_barrier per K-tile, vmcnt(4) steady state
// (never 0 until the final tile). 2-bit XOR swizzle (r7-verified family, 0 conflicts).
// Projections back to xconv + bf16-A; W2 fusion (r9, verified) kept.
//
// Per-tile schedule (hazard-traced):
//   lgkmcnt(0)            own prev ds_reads done
//   vmcnt(4 | 0 at last)  own tile-t loads landed (t+1 in flight stays)
//   s_barrier             => ALL waves: t staged, t-1 reads done
//   issue 4 gload16 (t+2 -> slot (t-1)%3)   WAR-safe behind barrier
//   ds_read 8 frags from slot t%3; 16 MFMA
//
// Workspace layout (bytes):
//   0        : Wq_b (1179648)   1179648: Wk_b   2359296: Wv_b   3538944: Wo_b
//   4718592  : Qb   [32768,768] bf16 relu'd   (50331648)
//   55050240 : Kb   [32768,768] bf16 relu'd   (reused as W2t [4][768][768] bf16)
//   105381888: Vb   [32768,768] bf16
//   155713536: P    partial KVt [48*16][64e*64d] f32 (12582912)
//   168296448: KVde [48][64d*64e] bf16 (393216)

#define H_  12
#define DH  64
#define E_  768
#define S_  8192
#define B_  4

typedef unsigned short u16;
typedef __attribute__((ext_vector_type(4))) float f32x4;
typedef __attribute__((ext_vector_type(4))) u16   u16x4;
typedef __attribute__((ext_vector_type(8))) u16   u16x8;
typedef __attribute__((ext_vector_type(8))) short s16x8;

static __device__ __forceinline__ u16 f2bf(float f) {
    __hip_bfloat16 h = __float2bfloat16(f);
    u16 r; __builtin_memcpy(&r, &h, 2); return r;
}
static __device__ __forceinline__ float bf2f(u16 u) {
    unsigned int i = ((unsigned int)u) << 16;
    float f; __builtin_memcpy(&f, &i, 4); return f;
}

static __device__ __forceinline__ void gload16(const void* g, void* lds) {
    __builtin_amdgcn_global_load_lds(
        (const __attribute__((address_space(1))) unsigned int*)(uintptr_t)g,
        (__attribute__((address_space(3))) unsigned int*)(uintptr_t)lds,
        16, 0, 0);
}

// ---------------- weight f32 -> bf16 ----------------
__global__ __launch_bounds__(256) void wconv(const float* __restrict__ in,
                                             u16* __restrict__ out, int n) {
    int i = (blockIdx.x * 256 + threadIdx.x) * 4;
    if (i + 3 < n) {
        f32x4 v = *(const f32x4*)&in[i];
        u16x4 o;
        o[0] = f2bf(v[0]); o[1] = f2bf(v[1]); o[2] = f2bf(v[2]); o[3] = f2bf(v[3]);
        *(u16x4*)&out[i] = o;
    }
}

// ---------------- input f32 -> bf16 ----------------
__global__ __launch_bounds__(256) void xconv(const float* __restrict__ in,
                                             u16* __restrict__ out) {
    long i = ((long)blockIdx.x * 256 + threadIdx.x) * 8;
    f32x4 a = *(const f32x4*)&in[i];
    f32x4 b = *(const f32x4*)&in[i + 4];
    u16x8 o;
    o[0] = f2bf(a[0]); o[1] = f2bf(a[1]); o[2] = f2bf(a[2]); o[3] = f2bf(a[3]);
    o[4] = f2bf(b[0]); o[5] = f2bf(b[1]); o[6] = f2bf(b[2]); o[7] = f2bf(b[3]);
    *(u16x8*)&out[i] = o;
}

// ---------------- gemm3: deep-pipelined bf16 MFMA GEMM, NT ----------------
// BM=BN=128, BK=32, 4 waves (2x2), wave tile 64x64, acc[4][4].
// LDS: As[3][128*32] + Bs[3][128*32] = 48 KB. Swizzle: phys = lo ^ (((lo>>6)&3)<<4)
// (16B slot index XOR low row bits; 64-B rows). gload dest linear, source
// pre-unswizzled (rule #21); reads use swizzled addr.
template<int RELU, int OUT_F32, int PERB>
__global__ __launch_bounds__(256, 3) void gemm3(const u16* __restrict__ A,
                                                const u16* __restrict__ Bw0,
                                                const float* __restrict__ bias,
                                                void* __restrict__ Cp, int K) {
    __shared__ u16 As[3][128 * 32];
    __shared__ u16 Bs[3][128 * 32];
    const int  t    = threadIdx.x;
    const int  lane = t & 63;
    const int  wave = t >> 6;
    const long m0   = (long)blockIdx.x * 128;
    const long n0   = (long)blockIdx.y * 128;
    const int  wr   = (wave >> 1) * 64;
    const int  wc   = (wave & 1) * 64;
    const int  N    = gridDim.y * 128;
    const u16* Bw   = PERB ? (Bw0 + (m0 >> 13) * 589824L) : Bw0;

    // staging: 8 chunks of 1 KB per operand tile, 2 per wave.
    // phys o = chunk*1024 + lane*16; logical lo = o ^ (((o>>6)&3)<<4);
    // row = lo>>6 (64 B/row), col = (lo&63)/2.
    const u16* srcA[2]; const u16* srcB[2]; int dstc[2];
    #pragma unroll
    for (int c = 0; c < 2; ++c) {
        int ch  = wave * 2 + c;
        int o   = ch * 1024 + lane * 16;
        int lo  = o ^ (((o >> 6) & 3) << 4);
        int row = lo >> 6, colb = lo & 63;
        dstc[c] = ch * 1024;
        srcA[c] = A  + (m0 + row) * (long)K + (colb >> 1);
        srcB[c] = Bw + (n0 + row) * (long)K + (colb >> 1);
    }

    // swizzled frag-read offsets: addr = (rowblk + lane&15)*64 + (kg*16 ^ ((lane&3)<<4))
    const int rbase = (lane & 15) * 64;
    const int koff  = ((lane >> 4) * 16) ^ ((lane & 3) << 4);

    f32x4 acc[4][4] = {};

    const int nt = K >> 5;   // 24 for K=768
    // prologue: stage tiles 0 and 1 into slots 0 and 1
    #pragma unroll
    for (int c = 0; c < 2; ++c) gload16(srcA[c],      (char*)&As[0][0] + dstc[c]);
    #pragma unroll
    for (int c = 0; c < 2; ++c) gload16(srcB[c],      (char*)&Bs[0][0] + dstc[c]);
    #pragma unroll
    for (int c = 0; c < 2; ++c) gload16(srcA[c] + 32, (char*)&As[1][0] + dstc[c]);
    #pragma unroll
    for (int c = 0; c < 2; ++c) gload16(srcB[c] + 32, (char*)&Bs[1][0] + dstc[c]);

    int sl = 0;
    for (int tt = 0; tt < nt; ++tt) {
        // own prev-tile ds_reads complete (so barrier-exit implies all waves done)
        asm volatile("s_waitcnt lgkmcnt(0)" ::: "memory");
        // own tile-tt loads landed; tile tt+1 (4 loads) stays in flight
        if (tt < nt - 1) asm volatile("s_waitcnt vmcnt(4)" ::: "memory");
        else             asm volatile("s_waitcnt vmcnt(0)" ::: "memory");
        asm volatile("s_barrier" ::: "memory");

        // stage tile tt+2 into slot (tt+2)%3 == (tt-1)%3 (readers finished pre-barrier)
        if (tt + 2 < nt) {
            const int  isl = (sl == 0) ? 2 : sl - 1;
            const long k0  = (long)(tt + 2) * 32;
            char* la = (char*)&As[isl][0];
            char* lb = (char*)&Bs[isl][0];
            #pragma unroll
            for (int c = 0; c < 2; ++c) gload16(srcA[c] + k0, la + dstc[c]);
            #pragma unroll
            for (int c = 0; c < 2; ++c) gload16(srcB[c] + k0, lb + dstc[c]);
        }

        const char* as = (const char*)&As[sl][0];
        const char* bs = (const char*)&Bs[sl][0];
        s16x8 af[4], bf[4];
        #pragma unroll
        for (int mi = 0; mi < 4; ++mi)
            af[mi] = *(const s16x8*)(as + (wr + mi * 16) * 64 + rbase + koff);
        #pragma unroll
        for (int ni = 0; ni < 4; ++ni)
            bf[ni] = *(const s16x8*)(bs + (wc + ni * 16) * 64 + rbase + koff);

        __builtin_amdgcn_s_setprio(1);
        #pragma unroll
        for (int mi = 0; mi < 4; ++mi)
            #pragma unroll
            for (int ni = 0; ni < 4; ++ni)
                acc[mi][ni] = __builtin_amdgcn_mfma_f32_16x16x32_bf16(af[mi], bf[ni], acc[mi][ni], 0, 0, 0);
        __builtin_amdgcn_s_setprio(0);

        sl = (sl == 2) ? 0 : sl + 1;
    }

    // epilogue: C/D layout col = lane&15, row = (lane>>4)*4 + r  (verified)
    const int cc = lane & 15;
    const int cr = (lane >> 4) * 4;
    float bv[4];
    #pragma unroll
    for (int ni = 0; ni < 4; ++ni) bv[ni] = bias[n0 + wc + ni * 16 + cc];
    #pragma unroll
    for (int mi = 0; mi < 4; ++mi) {
        #pragma unroll
        for (int r = 0; r < 4; ++r) {
            long gm = m0 + wr + mi * 16 + cr + r;
            #pragma unroll
            for (int ni = 0; ni < 4; ++ni) {
                long gn = n0 + wc + ni * 16 + cc;
                float v = acc[mi][ni][r] + bv[ni];
                if (RELU) v = fmaxf(v, 0.0f);
                if (OUT_F32) ((float*)Cp)[gm * N + gn] = v;
                else         ((u16*)Cp)[gm * N + gn]   = f2bf(v);
            }
        }
    }
}

// ---------------- KV partial v2 (verified): P[bhc][e][d] = sum_l V[l,e]*K[l,d] -------
__global__ __launch_bounds__(256) void kv_partial2(const u16* __restrict__ Kb,
                                                   const u16* __restrict__ Vb,
                                                   float* __restrict__ P) {
    __shared__ float sbuf[8192];
    const int bh = blockIdx.x, ch = blockIdx.y;
    const int b = bh / H_, h = bh - b * H_;
    const int t = threadIdx.x, lane = t & 63, wave = t >> 6;
    float* Kf = sbuf + wave * 2048;
    float* Vf = Kf + 1024;
    const long base = ((long)b * S_) * E_ + h * DH;
    const int eB = (lane >> 3) * 8;
    const int dB = (lane & 7) * 8;

    f32x4 acc[8][2] = {};

    const int l0w = ch * 512 + wave * 128;
    for (int ss = 0; ss < 8; ++ss) {
        const int l0 = l0w + ss * 16;
        #pragma unroll
        for (int half = 0; half < 2; ++half) {
            int u  = lane + half * 64;
            int lr = u >> 3, c0 = (u & 7) * 8;
            long g = base + (long)(l0 + lr) * E_ + c0;
            u16x8 kk = *(const u16x8*)&Kb[g];
            u16x8 vv = *(const u16x8*)&Vb[g];
            f32x4 k0, k1, v0, v1;
            #pragma unroll
            for (int j = 0; j < 4; ++j) {
                k0[j] = bf2f(kk[j]); k1[j] = bf2f(kk[j + 4]);
                v0[j] = bf2f(vv[j]); v1[j] = bf2f(vv[j + 4]);
            }
            *(f32x4*)&Kf[lr * 64 + c0]     = k0;
            *(f32x4*)&Kf[lr * 64 + c0 + 4] = k1;
            *(f32x4*)&Vf[lr * 64 + c0]     = v0;
            *(f32x4*)&Vf[lr * 64 + c0 + 4] = v1;
        }
        #pragma unroll
        for (int l = 0; l < 16; ++l) {
            f32x4 e0 = *(const f32x4*)&Vf[l * 64 + eB];
            f32x4 e1 = *(const f32x4*)&Vf[l * 64 + eB + 4];
            f32x4 d0 = *(const f32x4*)&Kf[l * 64 + dB];
            f32x4 d1 = *(const f32x4*)&Kf[l * 64 + dB + 4];
            #pragma unroll
            for (int i = 0; i < 4; ++i) {
                acc[i][0]     += e0[i] * d0;  acc[i][1]     += e0[i] * d1;
                acc[i + 4][0] += e1[i] * d0;  acc[i + 4][1] += e1[i] * d1;
            }
        }
    }

    __syncthreads();
    if (wave >= 2) {
        float* r = sbuf + (wave - 2) * 4096;
        #pragma unroll
        for (int i = 0; i < 8; ++i) {
            *(f32x4*)&r[(eB + i) * 64 + dB]     = acc[i][0];
            *(f32x4*)&r[(eB + i) * 64 + dB + 4] = acc[i][1];
        }
    }
    __syncthreads();
    if (wave < 2) {
        const float* r = sbuf + wave * 4096;
        #pragma unroll
        for (int i = 0; i < 8; ++i) {
            acc[i][0] += *(const f32x4*)&r[(eB + i) * 64 + dB];
            acc[i][1] += *(const f32x4*)&r[(eB + i) * 64 + dB + 4];
        }
    }
    __syncthreads();
    if (wave == 1) {
        #pragma unroll
        for (int i = 0; i < 8; ++i) {
            *(f32x4*)&sbuf[(eB + i) * 64 + dB]     = acc[i][0];
            *(f32x4*)&sbuf[(eB + i) * 64 + dB + 4] = acc[i][1];
        }
    }
    __syncthreads();
    if (wave == 0) {
        float* Pp = &P[((long)(bh * 16 + ch)) * 4096];
        #pragma unroll
        for (int i = 0; i < 8; ++i) {
            f32x4 s0 = acc[i][0] + *(const f32x4*)&sbuf[(eB + i) * 64 + dB];
            f32x4 s1 = acc[i][1] + *(const f32x4*)&sbuf[(eB + i) * 64 + dB + 4];
            *(f32x4*)&Pp[(eB + i) * 64 + dB]     = s0;
            *(f32x4*)&Pp[(eB + i) * 64 + dB + 4] = s1;
        }
    }
}

// ---------------- KV reduce (transposing): KVde[bh][d*64+e] bf16 ----------------
__global__ __launch_bounds__(256) void kv_reduce2(const float* __restrict__ P,
                                                  u16* __restrict__ KVde) {
    const int bh = blockIdx.x, t = threadIdx.x;
    #pragma unroll
    for (int k = 0; k < 4; ++k) {
        int i = t * 4 + k * 1024;
        f32x4 s = {};
        for (int c = 0; c < 16; ++c) s += *(const f32x4*)&P[((long)(bh * 16 + c)) * 4096 + i];
        const int e = i >> 6, d0 = i & 63;
        #pragma unroll
        for (int j = 0; j < 4; ++j)
            KVde[(long)bh * 4096 + (d0 + j) * 64 + e] = f2bf(s[j]);
    }
}

// ---------------- w2prep (verified): W2t[b][n][(h,d)] = sum_e Wo[n][(h,e)]*KVde[b,h][d][e]
__global__ __launch_bounds__(256) void w2prep(const u16* __restrict__ Wo_b,
                                              const u16* __restrict__ KVde,
                                              u16* __restrict__ W2t) {
    __shared__ u16 Qs[256 * 64];
    __shared__ u16 Ks[64 * 64];
    const int t = threadIdx.x, lane = t & 63, wave = t >> 6;
    const int h = blockIdx.y, b = blockIdx.z;
    const int n0 = blockIdx.x * 256;

    {
        char* lq = (char*)Qs;
        #pragma unroll
        for (int j = 0; j < 8; ++j) {
            int ob = (wave * 8 + j) * 1024;
            int ol = ob + lane * 16;
            int row = ol >> 7, col = (ol & 127) >> 1;
            gload16(&Wo_b[(long)(n0 + row) * E_ + h * DH + col], lq + ob);
        }
        char* lk = (char*)Ks;
        #pragma unroll
        for (int j = 0; j < 2; ++j) {
            int ob = (wave * 2 + j) * 1024;
            int ol = ob + lane * 16;
            int row = ol >> 7, col = (ol & 127) >> 1;
            gload16(&KVde[((long)(b * H_ + h)) * 4096 + row * 64 + col], lk + ob);
        }
    }
    __syncthreads();

    f32x4 acc[4][4] = {};
    #pragma unroll
    for (int kk = 0; kk < 2; ++kk) {
        s16x8 af[4], bfr[4];
        #pragma unroll
        for (int mi = 0; mi < 4; ++mi)
            af[mi] = *(const s16x8*)&Qs[(wave * 64 + mi * 16 + (lane & 15)) * 64 + kk * 32 + (lane >> 4) * 8];
        #pragma unroll
        for (int ni = 0; ni < 4; ++ni)
            bfr[ni] = *(const s16x8*)&Ks[(ni * 16 + (lane & 15)) * 64 + kk * 32 + (lane >> 4) * 8];
        #pragma unroll
        for (int mi = 0; mi < 4; ++mi)
            #pragma unroll
            for (int ni = 0; ni < 4; ++ni)
                acc[mi][ni] = __builtin_amdgcn_mfma_f32_16x16x32_bf16(af[mi], bfr[ni], acc[mi][ni], 0, 0, 0);
    }

    const int cc = lane & 15, cr = (lane >> 4) * 4;
    u16* Wb = W2t + (long)b * 589824L;
    #pragma unroll
    for (int mi = 0; mi < 4; ++mi) {
        #pragma unroll
        for (int r = 0; r < 4; ++r) {
            long gm = n0 + wave * 64 + mi * 16 + cr + r;
            #pragma unroll
            for (int ni = 0; ni < 4; ++ni)
                Wb[gm * E_ + h * DH + ni * 16 + cc] = f2bf(acc[mi][ni][r]);
        }
    }
}

extern "C" void kernel_launch(void* const* d_in, const int* in_sizes, int n_in,
                              void* d_out, int out_size, void* d_ws, size_t ws_size,
                              hipStream_t stream) {
    const float* q  = (const float*)d_in[0];
    const float* k  = (const float*)d_in[1];
    const float* v  = (const float*)d_in[2];
    const float* Wq = (const float*)d_in[3];
    const float* bq = (const float*)d_in[4];
    const float* Wk = (const float*)d_in[5];
    const float* bk = (const float*)d_in[6];
    const float* Wv = (const float*)d_in[7];
    const float* bv = (const float*)d_in[8];
    const float* Wo = (const float*)d_in[9];
    const float* bo = (const float*)d_in[10];
    float* out = (float*)d_out;

    char* ws = (char*)d_ws;
    u16*   Wq_b = (u16*)(ws);
    u16*   Wk_b = (u16*)(ws + 1179648L);
    u16*   Wv_b = (u16*)(ws + 2359296L);
    u16*   Wo_b = (u16*)(ws + 3538944L);
    u16*   Qb   = (u16*)(ws + 4718592L);
    u16*   Kb   = (u16*)(ws + 55050240L);
    u16*   Vb   = (u16*)(ws + 105381888L);
    float* P    = (float*)(ws + 155713536L);
    u16*   KVde = (u16*)(ws + 168296448L);
    u16*   W2t  = Kb;            // Kb dead after kv_partial2 — reuse
    u16*   xb   = (u16*)d_out;   // d_out as conversion scratch; overwritten by final GEMM

    dim3 blk(256);
    wconv<<<576, blk, 0, stream>>>(Wq, Wq_b, 589824);
    wconv<<<576, blk, 0, stream>>>(Wk, Wk_b, 589824);
    wconv<<<576, blk, 0, stream>>>(Wv, Wv_b, 589824);
    wconv<<<576, blk, 0, stream>>>(Wo, Wo_b, 589824);

    dim3 g1(256, 6);  // M=32768/128, N=768/128
    xconv<<<12288, blk, 0, stream>>>(q, xb);
    gemm3<1, 0, 0><<<g1, blk, 0, stream>>>(xb, Wq_b, bq, Qb, 768);
    xconv<<<12288, blk, 0, stream>>>(k, xb);
    gemm3<1, 0, 0><<<g1, blk, 0, stream>>>(xb, Wk_b, bk, Kb, 768);
    xconv<<<12288, blk, 0, stream>>>(v, xb);
    gemm3<0, 0, 0><<<g1, blk, 0, stream>>>(xb, Wv_b, bv, Vb, 768);

    kv_partial2<<<dim3(48, 16), blk, 0, stream>>>(Kb, Vb, P);
    kv_reduce2<<<48, blk, 0, stream>>>(P, KVde);
    w2prep<<<dim3(3, 12, 4), blk, 0, stream>>>(Wo_b, KVde, W2t);

    gemm3<0, 1, 1><<<g1, blk, 0, stream>>>(Qb, W2t, bo, out, 768);
}

// Round 11
// 352.316 us; speedup vs baseline: 1.1176x; 1.1176x over previous
//
#include <hip/hip_runtime.h>
#include <hip/hip_bf16.h>
#include <string.h>

// PerformerAttention: out = (relu(xWq^T+bq) @ [relu(xWk^T+bk)^T @ (xWv^T+bv)]_per-head) Wo^T + bo
// B=4 S=8192 E=768 H=12 Dh=64.
// Round 11: gemm4 — 3-slot counted-vmcnt pipeline (r10, verified) + geometry fix:
// BM=128 BN=256, 4 waves, wave tile 64x128 (42.7 FLOP/LDS-byte vs r10's 32 -> LDS
// no longer the pole: per-CU 1129cy LDS vs 1032cy MFMA). Row-pairing swizzle
// (2 M-rows per 128-B LDS row, 3-bit XOR -> 2-way residual = free). N-inner grid
// order so the 3 N-blocks sharing an A-panel are dispatch-adjacent (L2/L3 hits).
//
// Per-tile schedule (hazard-traced, r10-verified):
//   lgkmcnt(0); vmcnt(6|0 last); s_barrier; stage tt+2 -> slot(tt-1); ds_read; MFMA.
//
// Workspace layout (bytes):
//   0        : Wq_b (1179648)   1179648: Wk_b   2359296: Wv_b   3538944: Wo_b
//   4718592  : Qb   [32768,768] bf16 relu'd   (50331648)
//   55050240 : Kb   [32768,768] bf16 relu'd   (reused as W2t [4][768][768] bf16)
//   105381888: Vb   [32768,768] bf16
//   155713536: P    partial KVt [48*16][64e*64d] f32 (12582912)
//   168296448: KVde [48][64d*64e] bf16 (393216)

#define H_  12
#define DH  64
#define E_  768
#define S_  8192
#define B_  4

typedef unsigned short u16;
typedef __attribute__((ext_vector_type(4))) float f32x4;
typedef __attribute__((ext_vector_type(4))) u16   u16x4;
typedef __attribute__((ext_vector_type(8))) u16   u16x8;
typedef __attribute__((ext_vector_type(8))) short s16x8;

static __device__ __forceinline__ u16 f2bf(float f) {
    __hip_bfloat16 h = __float2bfloat16(f);
    u16 r; __builtin_memcpy(&r, &h, 2); return r;
}
static __device__ __forceinline__ float bf2f(u16 u) {
    unsigned int i = ((unsigned int)u) << 16;
    float f; __builtin_memcpy(&f, &i, 4); return f;
}

static __device__ __forceinline__ void gload16(const void* g, void* lds) {
    __builtin_amdgcn_global_load_lds(
        (const __attribute__((address_space(1))) unsigned int*)(uintptr_t)g,
        (__attribute__((address_space(3))) unsigned int*)(uintptr_t)lds,
        16, 0, 0);
}

// ---------------- weight f32 -> bf16 ----------------
__global__ __launch_bounds__(256) void wconv(const float* __restrict__ in,
                                             u16* __restrict__ out, int n) {
    int i = (blockIdx.x * 256 + threadIdx.x) * 4;
    if (i + 3 < n) {
        f32x4 v = *(const f32x4*)&in[i];
        u16x4 o;
        o[0] = f2bf(v[0]); o[1] = f2bf(v[1]); o[2] = f2bf(v[2]); o[3] = f2bf(v[3]);
        *(u16x4*)&out[i] = o;
    }
}

// ---------------- input f32 -> bf16 ----------------
__global__ __launch_bounds__(256) void xconv(const float* __restrict__ in,
                                             u16* __restrict__ out) {
    long i = ((long)blockIdx.x * 256 + threadIdx.x) * 8;
    f32x4 a = *(const f32x4*)&in[i];
    f32x4 b = *(const f32x4*)&in[i + 4];
    u16x8 o;
    o[0] = f2bf(a[0]); o[1] = f2bf(a[1]); o[2] = f2bf(a[2]); o[3] = f2bf(a[3]);
    o[4] = f2bf(b[0]); o[5] = f2bf(b[1]); o[6] = f2bf(b[2]); o[7] = f2bf(b[3]);
    *(u16x8*)&out[i] = o;
}

// ---------------- gemm4: deep-pipelined bf16 MFMA GEMM, NT ----------------
// BM=128, BN=256, BK=32, 4 waves (2Mx2N), wave tile 64x128, acc[4][8].
// LDS tiles pack 2 rows per 128-B LDS-row: A 8 KB (64 lds-rows), B 16 KB (128).
// Swizzle: byte-in-row = (((row&1)<<6) | kbyte16) ^ (((row>>1)&7)<<4) — bijective,
// 2-way bank aliasing only (free). gload dest linear, source inverse-swizzled.
// 3 slots, stage 2 tiles ahead, 1 s_barrier/tile, vmcnt(6) steady (6 loads/wave/tile).
template<int RELU, int OUT_F32, int PERB>
__global__ __launch_bounds__(256, 2) void gemm4(const u16* __restrict__ A,
                                                const u16* __restrict__ Bw0,
                                                const float* __restrict__ bias,
                                                void* __restrict__ Cp, int K) {
    __shared__ u16 As[3][4096];   // 3 x 8 KB
    __shared__ u16 Bs[3][8192];   // 3 x 16 KB
    const int  t    = threadIdx.x;
    const int  lane = t & 63;
    const int  wave = t >> 6;
    const long m0   = (long)blockIdx.y * 128;
    const long n0   = (long)blockIdx.x * 256;
    const int  wr   = (wave >> 1) * 64;     // wave M-offset
    const int  wc   = (wave & 1) * 128;     // wave N-offset
    const int  N    = gridDim.x * 256;
    const u16* Bw   = PERB ? (Bw0 + (long)(blockIdx.y >> 6) * 589824L) : Bw0;

    // ---- staging descriptors: phys o -> logical (row,k) via involution ----
    // lrow = o>>7; bir = (o&127) ^ ((lrow&7)<<4); row = 2*lrow + (bir>>6); kb = bir&63.
    const u16* srcA[2]; int dstA[2];
    #pragma unroll
    for (int c = 0; c < 2; ++c) {
        int ch   = wave * 2 + c;              // A: 8 chunks of 1 KB
        int o    = ch * 1024 + lane * 16;
        int lrow = o >> 7;
        int bir  = (o & 127) ^ ((lrow & 7) << 4);
        int row  = 2 * lrow + (bir >> 6);
        dstA[c]  = ch * 1024;
        srcA[c]  = A + (m0 + row) * (long)K + ((bir & 63) >> 1);
    }
    const u16* srcB[4]; int dstB[4];
    #pragma unroll
    for (int c = 0; c < 4; ++c) {
        int ch   = wave * 4 + c;              // B: 16 chunks of 1 KB
        int o    = ch * 1024 + lane * 16;
        int lrow = o >> 7;
        int bir  = (o & 127) ^ ((lrow & 7) << 4);
        int row  = 2 * lrow + (bir >> 6);
        dstB[c]  = ch * 1024;
        srcB[c]  = Bw + (n0 + row) * (long)K + ((bir & 63) >> 1);
    }

    // ---- swizzled frag-read byte offsets ----
    const int kg16 = (lane >> 4) * 16;
    int aoff[4], boff[8];
    #pragma unroll
    for (int mi = 0; mi < 4; ++mi) {
        int m    = wr + mi * 16 + (lane & 15);
        int lrow = m >> 1;
        aoff[mi] = lrow * 128 + ((((m & 1) << 6) | kg16) ^ ((lrow & 7) << 4));
    }
    #pragma unroll
    for (int ni = 0; ni < 8; ++ni) {
        int n    = wc + ni * 16 + (lane & 15);
        int lrow = n >> 1;
        boff[ni] = lrow * 128 + ((((n & 1) << 6) | kg16) ^ ((lrow & 7) << 4));
    }

    f32x4 acc[4][8] = {};

    const int nt = K >> 5;   // 24 for K=768
    // prologue: stage tiles 0,1 into slots 0,1
    #pragma unroll
    for (int c = 0; c < 2; ++c) gload16(srcA[c],      (char*)&As[0][0] + dstA[c]);
    #pragma unroll
    for (int c = 0; c < 4; ++c) gload16(srcB[c],      (char*)&Bs[0][0] + dstB[c]);
    #pragma unroll
    for (int c = 0; c < 2; ++c) gload16(srcA[c] + 32, (char*)&As[1][0] + dstA[c]);
    #pragma unroll
    for (int c = 0; c < 4; ++c) gload16(srcB[c] + 32, (char*)&Bs[1][0] + dstB[c]);

    int sl = 0;
    for (int tt = 0; tt < nt; ++tt) {
        // own reads of tile tt-1 done -> slot(tt-1) reusable after barrier
        asm volatile("s_waitcnt lgkmcnt(0)" ::: "memory");
        // own 6 loads of tile tt landed; tile tt+1's 6 stay in flight
        if (tt < nt - 1) asm volatile("s_waitcnt vmcnt(6)" ::: "memory");
        else             asm volatile("s_waitcnt vmcnt(0)" ::: "memory");
        asm volatile("s_barrier" ::: "memory");

        // stage tile tt+2 into slot (tt+2)%3 == slot(tt-1)
        if (tt + 2 < nt) {
            const int  isl = (sl == 0) ? 2 : sl - 1;
            const long k0  = (long)(tt + 2) * 32;
            #pragma unroll
            for (int c = 0; c < 2; ++c) gload16(srcA[c] + k0, (char*)&As[isl][0] + dstA[c]);
            #pragma unroll
            for (int c = 0; c < 4; ++c) gload16(srcB[c] + k0, (char*)&Bs[isl][0] + dstB[c]);
        }

        const char* as = (const char*)&As[sl][0];
        const char* bs = (const char*)&Bs[sl][0];
        s16x8 af[4], bf[8];
        #pragma unroll
        for (int mi = 0; mi < 4; ++mi) af[mi] = *(const s16x8*)(as + aoff[mi]);
        #pragma unroll
        for (int ni = 0; ni < 8; ++ni) bf[ni] = *(const s16x8*)(bs + boff[ni]);

        __builtin_amdgcn_s_setprio(1);
        #pragma unroll
        for (int mi = 0; mi < 4; ++mi)
            #pragma unroll
            for (int ni = 0; ni < 8; ++ni)
                acc[mi][ni] = __builtin_amdgcn_mfma_f32_16x16x32_bf16(af[mi], bf[ni], acc[mi][ni], 0, 0, 0);
        __builtin_amdgcn_s_setprio(0);

        sl = (sl == 2) ? 0 : sl + 1;
    }

    // ---- epilogue: C/D layout col = lane&15, row = (lane>>4)*4 + r (verified) ----
    const int cc = lane & 15;
    const int cr = (lane >> 4) * 4;
    float bv[8];
    #pragma unroll
    for (int ni = 0; ni < 8; ++ni) bv[ni] = bias[n0 + wc + ni * 16 + cc];
    #pragma unroll
    for (int mi = 0; mi < 4; ++mi) {
        #pragma unroll
        for (int r = 0; r < 4; ++r) {
            long gm = m0 + wr + mi * 16 + cr + r;
            #pragma unroll
            for (int ni = 0; ni < 8; ++ni) {
                long gn = n0 + wc + ni * 16 + cc;
                float v = acc[mi][ni][r] + bv[ni];
                if (RELU) v = fmaxf(v, 0.0f);
                if (OUT_F32) ((float*)Cp)[gm * N + gn] = v;
                else         ((u16*)Cp)[gm * N + gn]   = f2bf(v);
            }
        }
    }
}

// ---------------- KV partial v2 (verified): P[bhc][e][d] = sum_l V[l,e]*K[l,d] -------
__global__ __launch_bounds__(256) void kv_partial2(const u16* __restrict__ Kb,
                                                   const u16* __restrict__ Vb,
                                                   float* __restrict__ P) {
    __shared__ float sbuf[8192];
    const int bh = blockIdx.x, ch = blockIdx.y;
    const int b = bh / H_, h = bh - b * H_;
    const int t = threadIdx.x, lane = t & 63, wave = t >> 6;
    float* Kf = sbuf + wave * 2048;
    float* Vf = Kf + 1024;
    const long base = ((long)b * S_) * E_ + h * DH;
    const int eB = (lane >> 3) * 8;
    const int dB = (lane & 7) * 8;

    f32x4 acc[8][2] = {};

    const int l0w = ch * 512 + wave * 128;
    for (int ss = 0; ss < 8; ++ss) {
        const int l0 = l0w + ss * 16;
        #pragma unroll
        for (int half = 0; half < 2; ++half) {
            int u  = lane + half * 64;
            int lr = u >> 3, c0 = (u & 7) * 8;
            long g = base + (long)(l0 + lr) * E_ + c0;
            u16x8 kk = *(const u16x8*)&Kb[g];
            u16x8 vv = *(const u16x8*)&Vb[g];
            f32x4 k0, k1, v0, v1;
            #pragma unroll
            for (int j = 0; j < 4; ++j) {
                k0[j] = bf2f(kk[j]); k1[j] = bf2f(kk[j + 4]);
                v0[j] = bf2f(vv[j]); v1[j] = bf2f(vv[j + 4]);
            }
            *(f32x4*)&Kf[lr * 64 + c0]     = k0;
            *(f32x4*)&Kf[lr * 64 + c0 + 4] = k1;
            *(f32x4*)&Vf[lr * 64 + c0]     = v0;
            *(f32x4*)&Vf[lr * 64 + c0 + 4] = v1;
        }
        #pragma unroll
        for (int l = 0; l < 16; ++l) {
            f32x4 e0 = *(const f32x4*)&Vf[l * 64 + eB];
            f32x4 e1 = *(const f32x4*)&Vf[l * 64 + eB + 4];
            f32x4 d0 = *(const f32x4*)&Kf[l * 64 + dB];
            f32x4 d1 = *(const f32x4*)&Kf[l * 64 + dB + 4];
            #pragma unroll
            for (int i = 0; i < 4; ++i) {
                acc[i][0]     += e0[i] * d0;  acc[i][1]     += e0[i] * d1;
                acc[i + 4][0] += e1[i] * d0;  acc[i + 4][1] += e1[i] * d1;
            }
        }
    }

    __syncthreads();
    if (wave >= 2) {
        float* r = sbuf + (wave - 2) * 4096;
        #pragma unroll
        for (int i = 0; i < 8; ++i) {
            *(f32x4*)&r[(eB + i) * 64 + dB]     = acc[i][0];
            *(f32x4*)&r[(eB + i) * 64 + dB + 4] = acc[i][1];
        }
    }
    __syncthreads();
    if (wave < 2) {
        const float* r = sbuf + wave * 4096;
        #pragma unroll
        for (int i = 0; i < 8; ++i) {
            acc[i][0] += *(const f32x4*)&r[(eB + i) * 64 + dB];
            acc[i][1] += *(const f32x4*)&r[(eB + i) * 64 + dB + 4];
        }
    }
    __syncthreads();
    if (wave == 1) {
        #pragma unroll
        for (int i = 0; i < 8; ++i) {
            *(f32x4*)&sbuf[(eB + i) * 64 + dB]     = acc[i][0];
            *(f32x4*)&sbuf[(eB + i) * 64 + dB + 4] = acc[i][1];
        }
    }
    __syncthreads();
    if (wave == 0) {
        float* Pp = &P[((long)(bh * 16 + ch)) * 4096];
        #pragma unroll
        for (int i = 0; i < 8; ++i) {
            f32x4 s0 = acc[i][0] + *(const f32x4*)&sbuf[(eB + i) * 64 + dB];
            f32x4 s1 = acc[i][1] + *(const f32x4*)&sbuf[(eB + i) * 64 + dB + 4];
            *(f32x4*)&Pp[(eB + i) * 64 + dB]     = s0;
            *(f32x4*)&Pp[(eB + i) * 64 + dB + 4] = s1;
        }
    }
}

// ---------------- KV reduce (transposing): KVde[bh][d*64+e] bf16 ----------------
__global__ __launch_bounds__(256) void kv_reduce2(const float* __restrict__ P,
                                                  u16* __restrict__ KVde) {
    const int bh = blockIdx.x, t = threadIdx.x;
    #pragma unroll
    for (int k = 0; k < 4; ++k) {
        int i = t * 4 + k * 1024;
        f32x4 s = {};
        for (int c = 0; c < 16; ++c) s += *(const f32x4*)&P[((long)(bh * 16 + c)) * 4096 + i];
        const int e = i >> 6, d0 = i & 63;
        #pragma unroll
        for (int j = 0; j < 4; ++j)
            KVde[(long)bh * 4096 + (d0 + j) * 64 + e] = f2bf(s[j]);
    }
}

// ---------------- w2prep (verified): W2t[b][n][(h,d)] = sum_e Wo[n][(h,e)]*KVde[b,h][d][e]
__global__ __launch_bounds__(256) void w2prep(const u16* __restrict__ Wo_b,
                                              const u16* __restrict__ KVde,
                                              u16* __restrict__ W2t) {
    __shared__ u16 Qs[256 * 64];
    __shared__ u16 Ks[64 * 64];
    const int t = threadIdx.x, lane = t & 63, wave = t >> 6;
    const int h = blockIdx.y, b = blockIdx.z;
    const int n0 = blockIdx.x * 256;

    {
        char* lq = (char*)Qs;
        #pragma unroll
        for (int j = 0; j < 8; ++j) {
            int ob = (wave * 8 + j) * 1024;
            int ol = ob + lane * 16;
            int row = ol >> 7, col = (ol & 127) >> 1;
            gload16(&Wo_b[(long)(n0 + row) * E_ + h * DH + col], lq + ob);
        }
        char* lk = (char*)Ks;
        #pragma unroll
        for (int j = 0; j < 2; ++j) {
            int ob = (wave * 2 + j) * 1024;
            int ol = ob + lane * 16;
            int row = ol >> 7, col = (ol & 127) >> 1;
            gload16(&KVde[((long)(b * H_ + h)) * 4096 + row * 64 + col], lk + ob);
        }
    }
    __syncthreads();

    f32x4 acc[4][4] = {};
    #pragma unroll
    for (int kk = 0; kk < 2; ++kk) {
        s16x8 af[4], bfr[4];
        #pragma unroll
        for (int mi = 0; mi < 4; ++mi)
            af[mi] = *(const s16x8*)&Qs[(wave * 64 + mi * 16 + (lane & 15)) * 64 + kk * 32 + (lane >> 4) * 8];
        #pragma unroll
        for (int ni = 0; ni < 4; ++ni)
            bfr[ni] = *(const s16x8*)&Ks[(ni * 16 + (lane & 15)) * 64 + kk * 32 + (lane >> 4) * 8];
        #pragma unroll
        for (int mi = 0; mi < 4; ++mi)
            #pragma unroll
            for (int ni = 0; ni < 4; ++ni)
                acc[mi][ni] = __builtin_amdgcn_mfma_f32_16x16x32_bf16(af[mi], bfr[ni], acc[mi][ni], 0, 0, 0);
    }

    const int cc = lane & 15, cr = (lane >> 4) * 4;
    u16* Wb = W2t + (long)b * 589824L;
    #pragma unroll
    for (int mi = 0; mi < 4; ++mi) {
        #pragma unroll
        for (int r = 0; r < 4; ++r) {
            long gm = n0 + wave * 64 + mi * 16 + cr + r;
            #pragma unroll
            for (int ni = 0; ni < 4; ++ni)
                Wb[gm * E_ + h * DH + ni * 16 + cc] = f2bf(acc[mi][ni][r]);
        }
    }
}

extern "C" void kernel_launch(void* const* d_in, const int* in_sizes, int n_in,
                              void* d_out, int out_size, void* d_ws, size_t ws_size,
                              hipStream_t stream) {
    const float* q  = (const float*)d_in[0];
    const float* k  = (const float*)d_in[1];
    const float* v  = (const float*)d_in[2];
    const float* Wq = (const float*)d_in[3];
    const float* bq = (const float*)d_in[4];
    const float* Wk = (const float*)d_in[5];
    const float* bk = (const float*)d_in[6];
    const float* Wv = (const float*)d_in[7];
    const float* bv = (const float*)d_in[8];
    const float* Wo = (const float*)d_in[9];
    const float* bo = (const float*)d_in[10];
    float* out = (float*)d_out;

    char* ws = (char*)d_ws;
    u16*   Wq_b = (u16*)(ws);
    u16*   Wk_b = (u16*)(ws + 1179648L);
    u16*   Wv_b = (u16*)(ws + 2359296L);
    u16*   Wo_b = (u16*)(ws + 3538944L);
    u16*   Qb   = (u16*)(ws + 4718592L);
    u16*   Kb   = (u16*)(ws + 55050240L);
    u16*   Vb   = (u16*)(ws + 105381888L);
    float* P    = (float*)(ws + 155713536L);
    u16*   KVde = (u16*)(ws + 168296448L);
    u16*   W2t  = Kb;            // Kb dead after kv_partial2 — reuse
    u16*   xb   = (u16*)d_out;   // d_out as conversion scratch; overwritten by final GEMM

    dim3 blk(256);
    wconv<<<576, blk, 0, stream>>>(Wq, Wq_b, 589824);
    wconv<<<576, blk, 0, stream>>>(Wk, Wk_b, 589824);
    wconv<<<576, blk, 0, stream>>>(Wv, Wv_b, 589824);
    wconv<<<576, blk, 0, stream>>>(Wo, Wo_b, 589824);

    dim3 g1(3, 256);  // x = N-blocks (768/256), y = M-blocks (32768/128); N-inner order
    xconv<<<12288, blk, 0, stream>>>(q, xb);
    gemm4<1, 0, 0><<<g1, blk, 0, stream>>>(xb, Wq_b, bq, Qb, 768);
    xconv<<<12288, blk, 0, stream>>>(k, xb);
    gemm4<1, 0, 0><<<g1, blk, 0, stream>>>(xb, Wk_b, bk, Kb, 768);
    xconv<<<12288, blk, 0, stream>>>(v, xb);
    gemm4<0, 0, 0><<<g1, blk, 0, stream>>>(xb, Wv_b, bv, Vb, 768);

    kv_partial2<<<dim3(48, 16), blk, 0, stream>>>(Kb, Vb, P);
    kv_reduce2<<<48, blk, 0, stream>>>(P, KVde);
    w2prep<<<dim3(3, 12, 4), blk, 0, stream>>>(Wo_b, KVde, W2t);

    gemm4<0, 1, 1><<<g1, blk, 0, stream>>>(Qb, W2t, bo, out, 768);
}

// Round 12
// 330.688 us; speedup vs baseline: 1.1907x; 1.0654x over previous
//
#include <hip/hip_runtime.h>
#include <hip/hip_bf16.h>
#include <string.h>

// PerformerAttention: out = (relu(xWq^T+bq) @ [relu(xWk^T+bk)^T @ (xWv^T+bv)]_per-head) Wo^T + bo
// B=4 S=8192 E=768 H=12 Dh=64.
// Round 12: gemm5 — r11's 3-slot counted-vmcnt pipeline (verified) +
//  (1) bijective XCD swizzle: the 3 N-blocks sharing an A-panel land on the SAME XCD,
//      temporally adjacent (768 = 8 XCD x 96; xcd=wgid&7, i=wgid>>3, m=xcd*32+i/3, n=i%3).
//  (2) AF32 path: f32 A read directly (coalesced f32x4 -> cvt -> swizzled ds_write,
//      1 tile ahead); kills xconv. vmcnt ledger: 8 VMEM/iter/wave (4 A-loads + 4 B-gloads);
//      steady vmcnt(8) keeps tile tt+1 in flight; full unroll (NT=24) makes reg parity static.
// Per-tile: lgkm(0); vmcnt(8|0); s_barrier; issue A-regs+B-gloads(tt+2); cvt+ds_write A(tt+1);
//           ds_read frags(tt); 32 MFMA.
//
// Workspace layout (bytes):
//   0        : Wq_b (1179648)   1179648: Wk_b   2359296: Wv_b   3538944: Wo_b
//   4718592  : Qb   [32768,768] bf16 relu'd   (50331648)
//   55050240 : Kb   [32768,768] bf16 relu'd   (reused as W2t [4][768][768] bf16)
//   105381888: Vb   [32768,768] bf16
//   155713536: P    partial KVt [48*16][64e*64d] f32 (12582912)
//   168296448: KVde [48][64d*64e] bf16 (393216)

#define H_  12
#define DH  64
#define E_  768
#define S_  8192
#define B_  4

typedef unsigned short u16;
typedef __attribute__((ext_vector_type(4))) float f32x4;
typedef __attribute__((ext_vector_type(4))) u16   u16x4;
typedef __attribute__((ext_vector_type(8))) u16   u16x8;
typedef __attribute__((ext_vector_type(8))) short s16x8;

static __device__ __forceinline__ u16 f2bf(float f) {
    __hip_bfloat16 h = __float2bfloat16(f);
    u16 r; __builtin_memcpy(&r, &h, 2); return r;
}
static __device__ __forceinline__ float bf2f(u16 u) {
    unsigned int i = ((unsigned int)u) << 16;
    float f; __builtin_memcpy(&f, &i, 4); return f;
}

static __device__ __forceinline__ void gload16(const void* g, void* lds) {
    __builtin_amdgcn_global_load_lds(
        (const __attribute__((address_space(1))) unsigned int*)(uintptr_t)g,
        (__attribute__((address_space(3))) unsigned int*)(uintptr_t)lds,
        16, 0, 0);
}

// ---------------- weight f32 -> bf16 ----------------
__global__ __launch_bounds__(256) void wconv(const float* __restrict__ in,
                                             u16* __restrict__ out, int n) {
    int i = (blockIdx.x * 256 + threadIdx.x) * 4;
    if (i + 3 < n) {
        f32x4 v = *(const f32x4*)&in[i];
        u16x4 o;
        o[0] = f2bf(v[0]); o[1] = f2bf(v[1]); o[2] = f2bf(v[2]); o[3] = f2bf(v[3]);
        *(u16x4*)&out[i] = o;
    }
}

// ---------------- gemm5: XCD-swizzled deep-pipelined bf16 MFMA GEMM, NT ----------------
// BM=128, BN=256, BK=32, K=768 fixed, 4 waves (2Mx2N), wave tile 64x128, acc[4][8].
// LDS rows pack 2 logical rows per 128 B; swizzle bir ^= ((lrow&7)<<4) (r11-verified, 0 confl).
// AF32: A reg-staged (thread t: row t>>1, 16 f32 at col (t&1)*16 -> 2 swizzled ds_write_b128).
template<int AF32, int RELU, int OUT_F32, int PERB>
__global__ __launch_bounds__(256, 2) void gemm5(const void* __restrict__ Ap,
                                                const u16* __restrict__ Bw0,
                                                const float* __restrict__ bias,
                                                void* __restrict__ Cp) {
    constexpr int K = 768, NT = 24;
    __shared__ u16 As[3][4096];   // 3 x 8 KB
    __shared__ u16 Bs[3][8192];   // 3 x 16 KB
    const int t = threadIdx.x, lane = t & 63, wave = t >> 6;

    // XCD swizzle: HW assigns XCD = dispatch_index % 8. Keep the 3 N-sharers of an
    // A-panel on one XCD, adjacent in time.
    const int phys = blockIdx.x;          // 0..767
    const int xcd  = phys & 7;
    const int ii   = phys >> 3;           // 0..95
    const int i3   = ii / 3;
    const int mblk = xcd * 32 + i3;       // 0..255
    const int nblk = ii - i3 * 3;         // 0..2
    const long m0  = (long)mblk * 128;
    const long n0  = (long)nblk * 256;
    const int  wr  = (wave >> 1) * 64;
    const int  wc  = (wave & 1) * 128;
    const u16* Bw  = PERB ? (Bw0 + (long)(mblk >> 6) * 589824L) : Bw0;

    // ---- B staging: 16 chunks of 1 KB, 4/wave; involuted source (r11-verified) ----
    const u16* srcB[4]; int dstB[4];
    #pragma unroll
    for (int c = 0; c < 4; ++c) {
        int ch   = wave * 4 + c;
        int o    = ch * 1024 + lane * 16;
        int lrow = o >> 7;
        int bir  = (o & 127) ^ ((lrow & 7) << 4);
        int row  = 2 * lrow + (bir >> 6);
        dstB[c]  = ch * 1024;
        srcB[c]  = Bw + (n0 + row) * (long)K + ((bir & 63) >> 1);
    }
    // ---- A staging descriptors ----
    const u16*   srcA[2]; int dstA[2];     // AF32 == 0 (gload path)
    const float* aptr = nullptr; int awr0 = 0, awr1 = 0;   // AF32 == 1 (reg path)
    if constexpr (AF32) {
        const int ar = t >> 1;             // logical row 0..127
        const int ac = (t & 1) * 16;       // f32 col
        aptr = (const float*)Ap + (m0 + ar) * (long)K + ac;
        const int lrow = ar >> 1;
        const int kb0  = (t & 1) * 32;
        awr0 = lrow * 128 + (((((ar & 1) << 6) | (kb0))      ) ^ ((lrow & 7) << 4));
        awr1 = lrow * 128 + (((((ar & 1) << 6) | (kb0 + 16)) ) ^ ((lrow & 7) << 4));
    } else {
        #pragma unroll
        for (int c = 0; c < 2; ++c) {
            int ch   = wave * 2 + c;
            int o    = ch * 1024 + lane * 16;
            int lrow = o >> 7;
            int bir  = (o & 127) ^ ((lrow & 7) << 4);
            int row  = 2 * lrow + (bir >> 6);
            dstA[c]  = ch * 1024;
            srcA[c]  = (const u16*)Ap + (m0 + row) * (long)K + ((bir & 63) >> 1);
        }
    }

    // ---- swizzled frag-read byte offsets (r11-verified layout) ----
    const int kg16 = (lane >> 4) * 16;
    int aoff[4], boff[8];
    #pragma unroll
    for (int mi = 0; mi < 4; ++mi) {
        int m    = wr + mi * 16 + (lane & 15);
        int lrow = m >> 1;
        aoff[mi] = lrow * 128 + ((((m & 1) << 6) | kg16) ^ ((lrow & 7) << 4));
    }
    #pragma unroll
    for (int ni = 0; ni < 8; ++ni) {
        int n    = wc + ni * 16 + (lane & 15);
        int lrow = n >> 1;
        boff[ni] = lrow * 128 + ((((n & 1) << 6) | kg16) ^ ((lrow & 7) << 4));
    }

    f32x4 acc[4][8] = {};
    f32x4 ra[2][4];   // A(n) lives in ra[n&1]; static parity via full unroll

    // ---- prologue ----
    if constexpr (AF32) {
        #pragma unroll
        for (int j = 0; j < 4; ++j) ra[0][j] = *(const f32x4*)(aptr + j * 4);          // A(0)
        #pragma unroll
        for (int c = 0; c < 4; ++c) gload16(srcB[c], (char*)&Bs[0][0] + dstB[c]);      // B(0)
        {   // cvt + write A(0) -> slot 0 (compiler waits its own vmcnt for ra[0])
            u16x8 o8;
            #pragma unroll
            for (int x = 0; x < 4; ++x) { o8[x] = f2bf(ra[0][0][x]); o8[x + 4] = f2bf(ra[0][1][x]); }
            *(u16x8*)((char*)&As[0][0] + awr0) = o8;
            #pragma unroll
            for (int x = 0; x < 4; ++x) { o8[x] = f2bf(ra[0][2][x]); o8[x + 4] = f2bf(ra[0][3][x]); }
            *(u16x8*)((char*)&As[0][0] + awr1) = o8;
        }
        #pragma unroll
        for (int j = 0; j < 4; ++j) ra[1][j] = *(const f32x4*)(aptr + 32 + j * 4);     // A(1)
        #pragma unroll
        for (int c = 0; c < 4; ++c) gload16(srcB[c] + 32, (char*)&Bs[1][0] + dstB[c]); // B(1)
    } else {
        #pragma unroll
        for (int c = 0; c < 2; ++c) gload16(srcA[c],      (char*)&As[0][0] + dstA[c]);
        #pragma unroll
        for (int c = 0; c < 4; ++c) gload16(srcB[c],      (char*)&Bs[0][0] + dstB[c]);
        #pragma unroll
        for (int c = 0; c < 2; ++c) gload16(srcA[c] + 32, (char*)&As[1][0] + dstA[c]);
        #pragma unroll
        for (int c = 0; c < 4; ++c) gload16(srcB[c] + 32, (char*)&Bs[1][0] + dstB[c]);
    }

    // ---- main loop (fully unrolled: slot & reg parity compile-time) ----
    #pragma unroll
    for (int tt = 0; tt < NT; ++tt) {
        asm volatile("s_waitcnt lgkmcnt(0)" ::: "memory");
        if (tt < NT - 1) {
            if constexpr (AF32) asm volatile("s_waitcnt vmcnt(8)" ::: "memory");
            else                asm volatile("s_waitcnt vmcnt(6)" ::: "memory");
        } else {
            asm volatile("s_waitcnt vmcnt(0)" ::: "memory");
        }
        asm volatile("s_barrier" ::: "memory");

        const int sl = tt % 3;
        if (tt + 2 < NT) {
            const int isl = (tt + 2) % 3;
            const int k0  = (tt + 2) * 32;
            if constexpr (AF32) {
                #pragma unroll
                for (int j = 0; j < 4; ++j) ra[tt & 1][j] = *(const f32x4*)(aptr + k0 + j * 4);
            } else {
                #pragma unroll
                for (int c = 0; c < 2; ++c) gload16(srcA[c] + k0, (char*)&As[isl][0] + dstA[c]);
            }
            #pragma unroll
            for (int c = 0; c < 4; ++c) gload16(srcB[c] + k0, (char*)&Bs[isl][0] + dstB[c]);
        }
        if constexpr (AF32) {
            if (tt + 1 < NT) {   // cvt + write A(tt+1) -> slot (tt+1)%3
                const int wsl = (tt + 1) % 3;
                const f32x4* rv = ra[(tt + 1) & 1];
                u16x8 o8;
                #pragma unroll
                for (int x = 0; x < 4; ++x) { o8[x] = f2bf(rv[0][x]); o8[x + 4] = f2bf(rv[1][x]); }
                *(u16x8*)((char*)&As[wsl][0] + awr0) = o8;
                #pragma unroll
                for (int x = 0; x < 4; ++x) { o8[x] = f2bf(rv[2][x]); o8[x + 4] = f2bf(rv[3][x]); }
                *(u16x8*)((char*)&As[wsl][0] + awr1) = o8;
            }
        }

        const char* as = (const char*)&As[sl][0];
        const char* bs = (const char*)&Bs[sl][0];
        s16x8 af[4], bf[8];
        #pragma unroll
        for (int mi = 0; mi < 4; ++mi) af[mi] = *(const s16x8*)(as + aoff[mi]);
        #pragma unroll
        for (int ni = 0; ni < 8; ++ni) bf[ni] = *(const s16x8*)(bs + boff[ni]);

        __builtin_amdgcn_s_setprio(1);
        #pragma unroll
        for (int mi = 0; mi < 4; ++mi)
            #pragma unroll
            for (int ni = 0; ni < 8; ++ni)
                acc[mi][ni] = __builtin_amdgcn_mfma_f32_16x16x32_bf16(af[mi], bf[ni], acc[mi][ni], 0, 0, 0);
        __builtin_amdgcn_s_setprio(0);
    }

    // ---- epilogue: C/D layout col = lane&15, row = (lane>>4)*4 + r (verified) ----
    const int cc = lane & 15;
    const int cr = (lane >> 4) * 4;
    float bv[8];
    #pragma unroll
    for (int ni = 0; ni < 8; ++ni) bv[ni] = bias[n0 + wc + ni * 16 + cc];
    #pragma unroll
    for (int mi = 0; mi < 4; ++mi) {
        #pragma unroll
        for (int r = 0; r < 4; ++r) {
            long gm = m0 + wr + mi * 16 + cr + r;
            #pragma unroll
            for (int ni = 0; ni < 8; ++ni) {
                long gn = n0 + wc + ni * 16 + cc;
                float v = acc[mi][ni][r] + bv[ni];
                if (RELU) v = fmaxf(v, 0.0f);
                if (OUT_F32) ((float*)Cp)[gm * 768 + gn] = v;
                else         ((u16*)Cp)[gm * 768 + gn]   = f2bf(v);
            }
        }
    }
}

// ---------------- KV partial v2 (verified): P[bhc][e][d] = sum_l V[l,e]*K[l,d] -------
__global__ __launch_bounds__(256) void kv_partial2(const u16* __restrict__ Kb,
                                                   const u16* __restrict__ Vb,
                                                   float* __restrict__ P) {
    __shared__ float sbuf[8192];
    const int bh = blockIdx.x, ch = blockIdx.y;
    const int b = bh / H_, h = bh - b * H_;
    const int t = threadIdx.x, lane = t & 63, wave = t >> 6;
    float* Kf = sbuf + wave * 2048;
    float* Vf = Kf + 1024;
    const long base = ((long)b * S_) * E_ + h * DH;
    const int eB = (lane >> 3) * 8;
    const int dB = (lane & 7) * 8;

    f32x4 acc[8][2] = {};

    const int l0w = ch * 512 + wave * 128;
    for (int ss = 0; ss < 8; ++ss) {
        const int l0 = l0w + ss * 16;
        #pragma unroll
        for (int half = 0; half < 2; ++half) {
            int u  = lane + half * 64;
            int lr = u >> 3, c0 = (u & 7) * 8;
            long g = base + (long)(l0 + lr) * E_ + c0;
            u16x8 kk = *(const u16x8*)&Kb[g];
            u16x8 vv = *(const u16x8*)&Vb[g];
            f32x4 k0, k1, v0, v1;
            #pragma unroll
            for (int j = 0; j < 4; ++j) {
                k0[j] = bf2f(kk[j]); k1[j] = bf2f(kk[j + 4]);
                v0[j] = bf2f(vv[j]); v1[j] = bf2f(vv[j + 4]);
            }
            *(f32x4*)&Kf[lr * 64 + c0]     = k0;
            *(f32x4*)&Kf[lr * 64 + c0 + 4] = k1;
            *(f32x4*)&Vf[lr * 64 + c0]     = v0;
            *(f32x4*)&Vf[lr * 64 + c0 + 4] = v1;
        }
        #pragma unroll
        for (int l = 0; l < 16; ++l) {
            f32x4 e0 = *(const f32x4*)&Vf[l * 64 + eB];
            f32x4 e1 = *(const f32x4*)&Vf[l * 64 + eB + 4];
            f32x4 d0 = *(const f32x4*)&Kf[l * 64 + dB];
            f32x4 d1 = *(const f32x4*)&Kf[l * 64 + dB + 4];
            #pragma unroll
            for (int i = 0; i < 4; ++i) {
                acc[i][0]     += e0[i] * d0;  acc[i][1]     += e0[i] * d1;
                acc[i + 4][0] += e1[i] * d0;  acc[i + 4][1] += e1[i] * d1;
            }
        }
    }

    __syncthreads();
    if (wave >= 2) {
        float* r = sbuf + (wave - 2) * 4096;
        #pragma unroll
        for (int i = 0; i < 8; ++i) {
            *(f32x4*)&r[(eB + i) * 64 + dB]     = acc[i][0];
            *(f32x4*)&r[(eB + i) * 64 + dB + 4] = acc[i][1];
        }
    }
    __syncthreads();
    if (wave < 2) {
        const float* r = sbuf + wave * 4096;
        #pragma unroll
        for (int i = 0; i < 8; ++i) {
            acc[i][0] += *(const f32x4*)&r[(eB + i) * 64 + dB];
            acc[i][1] += *(const f32x4*)&r[(eB + i) * 64 + dB + 4];
        }
    }
    __syncthreads();
    if (wave == 1) {
        #pragma unroll
        for (int i = 0; i < 8; ++i) {
            *(f32x4*)&sbuf[(eB + i) * 64 + dB]     = acc[i][0];
            *(f32x4*)&sbuf[(eB + i) * 64 + dB + 4] = acc[i][1];
        }
    }
    __syncthreads();
    if (wave == 0) {
        float* Pp = &P[((long)(bh * 16 + ch)) * 4096];
        #pragma unroll
        for (int i = 0; i < 8; ++i) {
            f32x4 s0 = acc[i][0] + *(const f32x4*)&sbuf[(eB + i) * 64 + dB];
            f32x4 s1 = acc[i][1] + *(const f32x4*)&sbuf[(eB + i) * 64 + dB + 4];
            *(f32x4*)&Pp[(eB + i) * 64 + dB]     = s0;
            *(f32x4*)&Pp[(eB + i) * 64 + dB + 4] = s1;
        }
    }
}

// ---------------- KV reduce (transposing): KVde[bh][d*64+e] bf16 ----------------
__global__ __launch_bounds__(256) void kv_reduce2(const float* __restrict__ P,
                                                  u16* __restrict__ KVde) {
    const int bh = blockIdx.x, t = threadIdx.x;
    #pragma unroll
    for (int k = 0; k < 4; ++k) {
        int i = t * 4 + k * 1024;
        f32x4 s = {};
        for (int c = 0; c < 16; ++c) s += *(const f32x4*)&P[((long)(bh * 16 + c)) * 4096 + i];
        const int e = i >> 6, d0 = i & 63;
        #pragma unroll
        for (int j = 0; j < 4; ++j)
            KVde[(long)bh * 4096 + (d0 + j) * 64 + e] = f2bf(s[j]);
    }
}

// ---------------- w2prep (verified): W2t[b][n][(h,d)] = sum_e Wo[n][(h,e)]*KVde[b,h][d][e]
__global__ __launch_bounds__(256) void w2prep(const u16* __restrict__ Wo_b,
                                              const u16* __restrict__ KVde,
                                              u16* __restrict__ W2t) {
    __shared__ u16 Qs[256 * 64];
    __shared__ u16 Ks[64 * 64];
    const int t = threadIdx.x, lane = t & 63, wave = t >> 6;
    const int h = blockIdx.y, b = blockIdx.z;
    const int n0 = blockIdx.x * 256;

    {
        char* lq = (char*)Qs;
        #pragma unroll
        for (int j = 0; j < 8; ++j) {
            int ob = (wave * 8 + j) * 1024;
            int ol = ob + lane * 16;
            int row = ol >> 7, col = (ol & 127) >> 1;
            gload16(&Wo_b[(long)(n0 + row) * E_ + h * DH + col], lq + ob);
        }
        char* lk = (char*)Ks;
        #pragma unroll
        for (int j = 0; j < 2; ++j) {
            int ob = (wave * 2 + j) * 1024;
            int ol = ob + lane * 16;
            int row = ol >> 7, col = (ol & 127) >> 1;
            gload16(&KVde[((long)(b * H_ + h)) * 4096 + row * 64 + col], lk + ob);
        }
    }
    __syncthreads();

    f32x4 acc[4][4] = {};
    #pragma unroll
    for (int kk = 0; kk < 2; ++kk) {
        s16x8 af[4], bfr[4];
        #pragma unroll
        for (int mi = 0; mi < 4; ++mi)
            af[mi] = *(const s16x8*)&Qs[(wave * 64 + mi * 16 + (lane & 15)) * 64 + kk * 32 + (lane >> 4) * 8];
        #pragma unroll
        for (int ni = 0; ni < 4; ++ni)
            bfr[ni] = *(const s16x8*)&Ks[(ni * 16 + (lane & 15)) * 64 + kk * 32 + (lane >> 4) * 8];
        #pragma unroll
        for (int mi = 0; mi < 4; ++mi)
            #pragma unroll
            for (int ni = 0; ni < 4; ++ni)
                acc[mi][ni] = __builtin_amdgcn_mfma_f32_16x16x32_bf16(af[mi], bfr[ni], acc[mi][ni], 0, 0, 0);
    }

    const int cc = lane & 15, cr = (lane >> 4) * 4;
    u16* Wb = W2t + (long)b * 589824L;
    #pragma unroll
    for (int mi = 0; mi < 4; ++mi) {
        #pragma unroll
        for (int r = 0; r < 4; ++r) {
            long gm = n0 + wave * 64 + mi * 16 + cr + r;
            #pragma unroll
            for (int ni = 0; ni < 4; ++ni)
                Wb[gm * E_ + h * DH + ni * 16 + cc] = f2bf(acc[mi][ni][r]);
        }
    }
}

extern "C" void kernel_launch(void* const* d_in, const int* in_sizes, int n_in,
                              void* d_out, int out_size, void* d_ws, size_t ws_size,
                              hipStream_t stream) {
    const float* q  = (const float*)d_in[0];
    const float* k  = (const float*)d_in[1];
    const float* v  = (const float*)d_in[2];
    const float* Wq = (const float*)d_in[3];
    const float* bq = (const float*)d_in[4];
    const float* Wk = (const float*)d_in[5];
    const float* bk = (const float*)d_in[6];
    const float* Wv = (const float*)d_in[7];
    const float* bv = (const float*)d_in[8];
    const float* Wo = (const float*)d_in[9];
    const float* bo = (const float*)d_in[10];
    float* out = (float*)d_out;

    char* ws = (char*)d_ws;
    u16*   Wq_b = (u16*)(ws);
    u16*   Wk_b = (u16*)(ws + 1179648L);
    u16*   Wv_b = (u16*)(ws + 2359296L);
    u16*   Wo_b = (u16*)(ws + 3538944L);
    u16*   Qb   = (u16*)(ws + 4718592L);
    u16*   Kb   = (u16*)(ws + 55050240L);
    u16*   Vb   = (u16*)(ws + 105381888L);
    float* P    = (float*)(ws + 155713536L);
    u16*   KVde = (u16*)(ws + 168296448L);
    u16*   W2t  = Kb;   // Kb dead after kv_partial2 — reuse

    dim3 blk(256);
    wconv<<<576, blk, 0, stream>>>(Wq, Wq_b, 589824);
    wconv<<<576, blk, 0, stream>>>(Wk, Wk_b, 589824);
    wconv<<<576, blk, 0, stream>>>(Wv, Wv_b, 589824);
    wconv<<<576, blk, 0, stream>>>(Wo, Wo_b, 589824);

    // 768 = 256 M-blocks x 3 N-blocks, XCD-swizzled inside the kernel
    gemm5<1, 1, 0, 0><<<768, blk, 0, stream>>>(q, Wq_b, bq, Qb);
    gemm5<1, 1, 0, 0><<<768, blk, 0, stream>>>(k, Wk_b, bk, Kb);
    gemm5<1, 0, 0, 0><<<768, blk, 0, stream>>>(v, Wv_b, bv, Vb);

    kv_partial2<<<dim3(48, 16), blk, 0, stream>>>(Kb, Vb, P);
    kv_reduce2<<<48, blk, 0, stream>>>(P, KVde);
    w2prep<<<dim3(3, 12, 4), blk, 0, stream>>>(Wo_b, KVde, W2t);

    gemm5<0, 0, 1, 1><<<768, blk, 0, stream>>>(Qb, W2t, bo, out);
}

// Round 13
// 330.108 us; speedup vs baseline: 1.1928x; 1.0018x over previous
//
#include <hip/hip_runtime.h>
#include <hip/hip_bf16.h>
#include <string.h>

// PerformerAttention: out = (relu(xWq^T+bq) @ [relu(xWk^T+bk)^T @ (xWv^T+bv)]_per-head) Wo^T + bo
// B=4 S=8192 E=768 H=12 Dh=64.
// Round 12: gemm5 — r11's 3-slot counted-vmcnt pipeline (verified) +
//  (1) bijective XCD swizzle: the 3 N-blocks sharing an A-panel land on the SAME XCD,
//      temporally adjacent (768 = 8 XCD x 96; xcd=wgid&7, i=wgid>>3, m=xcd*32+i/3, n=i%3).
//  (2) AF32 path: f32 A read directly (coalesced f32x4 -> cvt -> swizzled ds_write,
//      1 tile ahead); kills xconv. vmcnt ledger: 8 VMEM/iter/wave (4 A-loads + 4 B-gloads);
//      steady vmcnt(8) keeps tile tt+1 in flight; full unroll (NT=24) makes reg parity static.
// Per-tile: lgkm(0); vmcnt(8|0); s_barrier; issue A-regs+B-gloads(tt+2); cvt+ds_write A(tt+1);
//           ds_read frags(tt); 32 MFMA.
//
// Workspace layout (bytes):
//   0        : Wq_b (1179648)   1179648: Wk_b   2359296: Wv_b   3538944: Wo_b
//   4718592  : Qb   [32768,768] bf16 relu'd   (50331648)
//   55050240 : Kb   [32768,768] bf16 relu'd   (reused as W2t [4][768][768] bf16)
//   105381888: Vb   [32768,768] bf16
//   155713536: P    partial KVt [48*16][64e*64d] f32 (12582912)
//   168296448: KVde [48][64d*64e] bf16 (393216)

#define H_  12
#define DH  64
#define E_  768
#define S_  8192
#define B_  4

typedef unsigned short u16;
typedef __attribute__((ext_vector_type(4))) float f32x4;
typedef __attribute__((ext_vector_type(4))) u16   u16x4;
typedef __attribute__((ext_vector_type(8))) u16   u16x8;
typedef __attribute__((ext_vector_type(8))) short s16x8;

static __device__ __forceinline__ u16 f2bf(float f) {
    __hip_bfloat16 h = __float2bfloat16(f);
    u16 r; __builtin_memcpy(&r, &h, 2); return r;
}
static __device__ __forceinline__ float bf2f(u16 u) {
    unsigned int i = ((unsigned int)u) << 16;
    float f; __builtin_memcpy(&f, &i, 4); return f;
}

static __device__ __forceinline__ void gload16(const void* g, void* lds) {
    __builtin_amdgcn_global_load_lds(
        (const __attribute__((address_space(1))) unsigned int*)(uintptr_t)g,
        (__attribute__((address_space(3))) unsigned int*)(uintptr_t)lds,
        16, 0, 0);
}

// ---------------- weight f32 -> bf16 ----------------
__global__ __launch_bounds__(256) void wconv(const float* __restrict__ in,
                                             u16* __restrict__ out, int n) {
    int i = (blockIdx.x * 256 + threadIdx.x) * 4;
    if (i + 3 < n) {
        f32x4 v = *(const f32x4*)&in[i];
        u16x4 o;
        o[0] = f2bf(v[0]); o[1] = f2bf(v[1]); o[2] = f2bf(v[2]); o[3] = f2bf(v[3]);
        *(u16x4*)&out[i] = o;
    }
}

// ---------------- gemm5: XCD-swizzled deep-pipelined bf16 MFMA GEMM, NT ----------------
// BM=128, BN=256, BK=32, K=768 fixed, 4 waves (2Mx2N), wave tile 64x128, acc[4][8].
// LDS rows pack 2 logical rows per 128 B; swizzle bir ^= ((lrow&7)<<4) (r11-verified, 0 confl).
// AF32: A reg-staged (thread t: row t>>1, 16 f32 at col (t&1)*16 -> 2 swizzled ds_write_b128).
template<int AF32, int RELU, int OUT_F32, int PERB>
__global__ __launch_bounds__(256, 2) void gemm5(const void* __restrict__ Ap,
                                                const u16* __restrict__ Bw0,
                                                const float* __restrict__ bias,
                                                void* __restrict__ Cp) {
    constexpr int K = 768, NT = 24;
    __shared__ u16 As[3][4096];   // 3 x 8 KB
    __shared__ u16 Bs[3][8192];   // 3 x 16 KB
    const int t = threadIdx.x, lane = t & 63, wave = t >> 6;

    // XCD swizzle: HW assigns XCD = dispatch_index % 8. Keep the 3 N-sharers of an
    // A-panel on one XCD, adjacent in time.
    const int phys = blockIdx.x;          // 0..767
    const int xcd  = phys & 7;
    const int ii   = phys >> 3;           // 0..95
    const int i3   = ii / 3;
    const int mblk = xcd * 32 + i3;       // 0..255
    const int nblk = ii - i3 * 3;         // 0..2
    const long m0  = (long)mblk * 128;
    const long n0  = (long)nblk * 256;
    const int  wr  = (wave >> 1) * 64;
    const int  wc  = (wave & 1) * 128;
    const u16* Bw  = PERB ? (Bw0 + (long)(mblk >> 6) * 589824L) : Bw0;

    // ---- B staging: 16 chunks of 1 KB, 4/wave; involuted source (r11-verified) ----
    const u16* srcB[4]; int dstB[4];
    #pragma unroll
    for (int c = 0; c < 4; ++c) {
        int ch   = wave * 4 + c;
        int o    = ch * 1024 + lane * 16;
        int lrow = o >> 7;
        int bir  = (o & 127) ^ ((lrow & 7) << 4);
        int row  = 2 * lrow + (bir >> 6);
        dstB[c]  = ch * 1024;
        srcB[c]  = Bw + (n0 + row) * (long)K + ((bir & 63) >> 1);
    }
    // ---- A staging descriptors ----
    const u16*   srcA[2]; int dstA[2];     // AF32 == 0 (gload path)
    const float* aptr = nullptr; int awr0 = 0, awr1 = 0;   // AF32 == 1 (reg path)
    if constexpr (AF32) {
        const int ar = t >> 1;             // logical row 0..127
        const int ac = (t & 1) * 16;       // f32 col
        aptr = (const float*)Ap + (m0 + ar) * (long)K + ac;
        const int lrow = ar >> 1;
        const int kb0  = (t & 1) * 32;
        awr0 = lrow * 128 + (((((ar & 1) << 6) | (kb0))      ) ^ ((lrow & 7) << 4));
        awr1 = lrow * 128 + (((((ar & 1) << 6) | (kb0 + 16)) ) ^ ((lrow & 7) << 4));
    } else {
        #pragma unroll
        for (int c = 0; c < 2; ++c) {
            int ch   = wave * 2 + c;
            int o    = ch * 1024 + lane * 16;
            int lrow = o >> 7;
            int bir  = (o & 127) ^ ((lrow & 7) << 4);
            int row  = 2 * lrow + (bir >> 6);
            dstA[c]  = ch * 1024;
            srcA[c]  = (const u16*)Ap + (m0 + row) * (long)K + ((bir & 63) >> 1);
        }
    }

    // ---- swizzled frag-read byte offsets (r11-verified layout) ----
    const int kg16 = (lane >> 4) * 16;
    int aoff[4], boff[8];
    #pragma unroll
    for (int mi = 0; mi < 4; ++mi) {
        int m    = wr + mi * 16 + (lane & 15);
        int lrow = m >> 1;
        aoff[mi] = lrow * 128 + ((((m & 1) << 6) | kg16) ^ ((lrow & 7) << 4));
    }
    #pragma unroll
    for (int ni = 0; ni < 8; ++ni) {
        int n    = wc + ni * 16 + (lane & 15);
        int lrow = n >> 1;
        boff[ni] = lrow * 128 + ((((n & 1) << 6) | kg16) ^ ((lrow & 7) << 4));
    }

    f32x4 acc[4][8] = {};
    f32x4 ra[2][4];   // A(n) lives in ra[n&1]; static parity via full unroll

    // ---- prologue ----
    if constexpr (AF32) {
        #pragma unroll
        for (int j = 0; j < 4; ++j) ra[0][j] = *(const f32x4*)(aptr + j * 4);          // A(0)
        #pragma unroll
        for (int c = 0; c < 4; ++c) gload16(srcB[c], (char*)&Bs[0][0] + dstB[c]);      // B(0)
        {   // cvt + write A(0) -> slot 0 (compiler waits its own vmcnt for ra[0])
            u16x8 o8;
            #pragma unroll
            for (int x = 0; x < 4; ++x) { o8[x] = f2bf(ra[0][0][x]); o8[x + 4] = f2bf(ra[0][1][x]); }
            *(u16x8*)((char*)&As[0][0] + awr0) = o8;
            #pragma unroll
            for (int x = 0; x < 4; ++x) { o8[x] = f2bf(ra[0][2][x]); o8[x + 4] = f2bf(ra[0][3][x]); }
            *(u16x8*)((char*)&As[0][0] + awr1) = o8;
        }
        #pragma unroll
        for (int j = 0; j < 4; ++j) ra[1][j] = *(const f32x4*)(aptr + 32 + j * 4);     // A(1)
        #pragma unroll
        for (int c = 0; c < 4; ++c) gload16(srcB[c] + 32, (char*)&Bs[1][0] + dstB[c]); // B(1)
    } else {
        #pragma unroll
        for (int c = 0; c < 2; ++c) gload16(srcA[c],      (char*)&As[0][0] + dstA[c]);
        #pragma unroll
        for (int c = 0; c < 4; ++c) gload16(srcB[c],      (char*)&Bs[0][0] + dstB[c]);
        #pragma unroll
        for (int c = 0; c < 2; ++c) gload16(srcA[c] + 32, (char*)&As[1][0] + dstA[c]);
        #pragma unroll
        for (int c = 0; c < 4; ++c) gload16(srcB[c] + 32, (char*)&Bs[1][0] + dstB[c]);
    }

    // ---- main loop (fully unrolled: slot & reg parity compile-time) ----
    #pragma unroll
    for (int tt = 0; tt < NT; ++tt) {
        asm volatile("s_waitcnt lgkmcnt(0)" ::: "memory");
        if (tt < NT - 1) {
            if constexpr (AF32) asm volatile("s_waitcnt vmcnt(8)" ::: "memory");
            else                asm volatile("s_waitcnt vmcnt(6)" ::: "memory");
        } else {
            asm volatile("s_waitcnt vmcnt(0)" ::: "memory");
        }
        asm volatile("s_barrier" ::: "memory");

        const int sl = tt % 3;
        if (tt + 2 < NT) {
            const int isl = (tt + 2) % 3;
            const int k0  = (tt + 2) * 32;
            if constexpr (AF32) {
                #pragma unroll
                for (int j = 0; j < 4; ++j) ra[tt & 1][j] = *(const f32x4*)(aptr + k0 + j * 4);
            } else {
                #pragma unroll
                for (int c = 0; c < 2; ++c) gload16(srcA[c] + k0, (char*)&As[isl][0] + dstA[c]);
            }
            #pragma unroll
            for (int c = 0; c < 4; ++c) gload16(srcB[c] + k0, (char*)&Bs[isl][0] + dstB[c]);
        }
        if constexpr (AF32) {
            if (tt + 1 < NT) {   // cvt + write A(tt+1) -> slot (tt+1)%3
                const int wsl = (tt + 1) % 3;
                const f32x4* rv = ra[(tt + 1) & 1];
                u16x8 o8;
                #pragma unroll
                for (int x = 0; x < 4; ++x) { o8[x] = f2bf(rv[0][x]); o8[x + 4] = f2bf(rv[1][x]); }
                *(u16x8*)((char*)&As[wsl][0] + awr0) = o8;
                #pragma unroll
                for (int x = 0; x < 4; ++x) { o8[x] = f2bf(rv[2][x]); o8[x + 4] = f2bf(rv[3][x]); }
                *(u16x8*)((char*)&As[wsl][0] + awr1) = o8;
            }
        }

        const char* as = (const char*)&As[sl][0];
        const char* bs = (const char*)&Bs[sl][0];
        s16x8 af[4], bf[8];
        #pragma unroll
        for (int mi = 0; mi < 4; ++mi) af[mi] = *(const s16x8*)(as + aoff[mi]);
        #pragma unroll
        for (int ni = 0; ni < 8; ++ni) bf[ni] = *(const s16x8*)(bs + boff[ni]);

        __builtin_amdgcn_s_setprio(1);
        #pragma unroll
        for (int mi = 0; mi < 4; ++mi)
            #pragma unroll
            for (int ni = 0; ni < 8; ++ni)
                acc[mi][ni] = __builtin_amdgcn_mfma_f32_16x16x32_bf16(af[mi], bf[ni], acc[mi][ni], 0, 0, 0);
        __builtin_amdgcn_s_setprio(0);
    }

    // ---- epilogue: C/D layout col = lane&15, row = (lane>>4)*4 + r (verified) ----
    const int cc = lane & 15;
    const int cr = (lane >> 4) * 4;
    float bv[8];
    #pragma unroll
    for (int ni = 0; ni < 8; ++ni) bv[ni] = bias[n0 + wc + ni * 16 + cc];
    #pragma unroll
    for (int mi = 0; mi < 4; ++mi) {
        #pragma unroll
        for (int r = 0; r < 4; ++r) {
            long gm = m0 + wr + mi * 16 + cr + r;
            #pragma unroll
            for (int ni = 0; ni < 8; ++ni) {
                long gn = n0 + wc + ni * 16 + cc;
                float v = acc[mi][ni][r] + bv[ni];
                if (RELU) v = fmaxf(v, 0.0f);
                if (OUT_F32) ((float*)Cp)[gm * 768 + gn] = v;
                else         ((u16*)Cp)[gm * 768 + gn]   = f2bf(v);
            }
        }
    }
}

// ---------------- KV partial v2 (verified): P[bhc][e][d] = sum_l V[l,e]*K[l,d] -------
__global__ __launch_bounds__(256) void kv_partial2(const u16* __restrict__ Kb,
                                                   const u16* __restrict__ Vb,
                                                   float* __restrict__ P) {
    __shared__ float sbuf[8192];
    const int bh = blockIdx.x, ch = blockIdx.y;
    const int b = bh / H_, h = bh - b * H_;
    const int t = threadIdx.x, lane = t & 63, wave = t >> 6;
    float* Kf = sbuf + wave * 2048;
    float* Vf = Kf + 1024;
    const long base = ((long)b * S_) * E_ + h * DH;
    const int eB = (lane >> 3) * 8;
    const int dB = (lane & 7) * 8;

    f32x4 acc[8][2] = {};

    const int l0w = ch * 512 + wave * 128;
    for (int ss = 0; ss < 8; ++ss) {
        const int l0 = l0w + ss * 16;
        #pragma unroll
        for (int half = 0; half < 2; ++half) {
            int u  = lane + half * 64;
            int lr = u >> 3, c0 = (u & 7) * 8;
            long g = base + (long)(l0 + lr) * E_ + c0;
            u16x8 kk = *(const u16x8*)&Kb[g];
            u16x8 vv = *(const u16x8*)&Vb[g];
            f32x4 k0, k1, v0, v1;
            #pragma unroll
            for (int j = 0; j < 4; ++j) {
                k0[j] = bf2f(kk[j]); k1[j] = bf2f(kk[j + 4]);
                v0[j] = bf2f(vv[j]); v1[j] = bf2f(vv[j + 4]);
            }
            *(f32x4*)&Kf[lr * 64 + c0]     = k0;
            *(f32x4*)&Kf[lr * 64 + c0 + 4] = k1;
            *(f32x4*)&Vf[lr * 64 + c0]     = v0;
            *(f32x4*)&Vf[lr * 64 + c0 + 4] = v1;
        }
        #pragma unroll
        for (int l = 0; l < 16; ++l) {
            f32x4 e0 = *(const f32x4*)&Vf[l * 64 + eB];
            f32x4 e1 = *(const f32x4*)&Vf[l * 64 + eB + 4];
            f32x4 d0 = *(const f32x4*)&Kf[l * 64 + dB];
            f32x4 d1 = *(const f32x4*)&Kf[l * 64 + dB + 4];
            #pragma unroll
            for (int i = 0; i < 4; ++i) {
                acc[i][0]     += e0[i] * d0;  acc[i][1]     += e0[i] * d1;
                acc[i + 4][0] += e1[i] * d0;  acc[i + 4][1] += e1[i] * d1;
            }
        }
    }

    __syncthreads();
    if (wave >= 2) {
        float* r = sbuf + (wave - 2) * 4096;
        #pragma unroll
        for (int i = 0; i < 8; ++i) {
            *(f32x4*)&r[(eB + i) * 64 + dB]     = acc[i][0];
            *(f32x4*)&r[(eB + i) * 64 + dB + 4] = acc[i][1];
        }
    }
    __syncthreads();
    if (wave < 2) {
        const float* r = sbuf + wave * 4096;
        #pragma unroll
        for (int i = 0; i < 8; ++i) {
            acc[i][0] += *(const f32x4*)&r[(eB + i) * 64 + dB];
            acc[i][1] += *(const f32x4*)&r[(eB + i) * 64 + dB + 4];
        }
    }
    __syncthreads();
    if (wave == 1) {
        #pragma unroll
        for (int i = 0; i < 8; ++i) {
            *(f32x4*)&sbuf[(eB + i) * 64 + dB]     = acc[i][0];
            *(f32x4*)&sbuf[(eB + i) * 64 + dB + 4] = acc[i][1];
        }
    }
    __syncthreads();
    if (wave == 0) {
        float* Pp = &P[((long)(bh * 16 + ch)) * 4096];
        #pragma unroll
        for (int i = 0; i < 8; ++i) {
            f32x4 s0 = acc[i][0] + *(const f32x4*)&sbuf[(eB + i) * 64 + dB];
            f32x4 s1 = acc[i][1] + *(const f32x4*)&sbuf[(eB + i) * 64 + dB + 4];
            *(f32x4*)&Pp[(eB + i) * 64 + dB]     = s0;
            *(f32x4*)&Pp[(eB + i) * 64 + dB + 4] = s1;
        }
    }
}

// ---------------- KV reduce (transposing): KVde[bh][d*64+e] bf16 ----------------
__global__ __launch_bounds__(256) void kv_reduce2(const float* __restrict__ P,
                                                  u16* __restrict__ KVde) {
    const int bh = blockIdx.x, t = threadIdx.x;
    #pragma unroll
    for (int k = 0; k < 4; ++k) {
        int i = t * 4 + k * 1024;
        f32x4 s = {};
        for (int c = 0; c < 16; ++c) s += *(const f32x4*)&P[((long)(bh * 16 + c)) * 4096 + i];
        const int e = i >> 6, d0 = i & 63;
        #pragma unroll
        for (int j = 0; j < 4; ++j)
            KVde[(long)bh * 4096 + (d0 + j) * 64 + e] = f2bf(s[j]);
    }
}

// ---------------- w2prep (verified): W2t[b][n][(h,d)] = sum_e Wo[n][(h,e)]*KVde[b,h][d][e]
__global__ __launch_bounds__(256) void w2prep(const u16* __restrict__ Wo_b,
                                              const u16* __restrict__ KVde,
                                              u16* __restrict__ W2t) {
    __shared__ u16 Qs[256 * 64];
    __shared__ u16 Ks[64 * 64];
    const int t = threadIdx.x, lane = t & 63, wave = t >> 6;
    const int h = blockIdx.y, b = blockIdx.z;
    const int n0 = blockIdx.x * 256;

    {
        char* lq = (char*)Qs;
        #pragma unroll
        for (int j = 0; j < 8; ++j) {
            int ob = (wave * 8 + j) * 1024;
            int ol = ob + lane * 16;
            int row = ol >> 7, col = (ol & 127) >> 1;
            gload16(&Wo_b[(long)(n0 + row) * E_ + h * DH + col], lq + ob);
        }
        char* lk = (char*)Ks;
        #pragma unroll
        for (int j = 0; j < 2; ++j) {
            int ob = (wave * 2 + j) * 1024;
            int ol = ob + lane * 16;
            int row = ol >> 7, col = (ol & 127) >> 1;
            gload16(&KVde[((long)(b * H_ + h)) * 4096 + row * 64 + col], lk + ob);
        }
    }
    __syncthreads();

    f32x4 acc[4][4] = {};
    #pragma unroll
    for (int kk = 0; kk < 2; ++kk) {
        s16x8 af[4], bfr[4];
        #pragma unroll
        for (int mi = 0; mi < 4; ++mi)
            af[mi] = *(const s16x8*)&Qs[(wave * 64 + mi * 16 + (lane & 15)) * 64 + kk * 32 + (lane >> 4) * 8];
        #pragma unroll
        for (int ni = 0; ni < 4; ++ni)
            bfr[ni] = *(const s16x8*)&Ks[(ni * 16 + (lane & 15)) * 64 + kk * 32 + (lane >> 4) * 8];
        #pragma unroll
        for (int mi = 0; mi < 4; ++mi)
            #pragma unroll
            for (int ni = 0; ni < 4; ++ni)
                acc[mi][ni] = __builtin_amdgcn_mfma_f32_16x16x32_bf16(af[mi], bfr[ni], acc[mi][ni], 0, 0, 0);
    }

    const int cc = lane & 15, cr = (lane >> 4) * 4;
    u16* Wb = W2t + (long)b * 589824L;
    #pragma unroll
    for (int mi = 0; mi < 4; ++mi) {
        #pragma unroll
        for (int r = 0; r < 4; ++r) {
            long gm = n0 + wave * 64 + mi * 16 + cr + r;
            #pragma unroll
            for (int ni = 0; ni < 4; ++ni)
                Wb[gm * E_ + h * DH + ni * 16 + cc] = f2bf(acc[mi][ni][r]);
        }
    }
}

extern "C" void kernel_launch(void* const* d_in, const int* in_sizes, int n_in,
                              void* d_out, int out_size, void* d_ws, size_t ws_size,
                              hipStream_t stream) {
    const float* q  = (const float*)d_in[0];
    const float* k  = (const float*)d_in[1];
    const float* v  = (const float*)d_in[2];
    const float* Wq = (const float*)d_in[3];
    const float* bq = (const float*)d_in[4];
    const float* Wk = (const float*)d_in[5];
    const float* bk = (const float*)d_in[6];
    const float* Wv = (const float*)d_in[7];
    const float* bv = (const float*)d_in[8];
    const float* Wo = (const float*)d_in[9];
    const float* bo = (const float*)d_in[10];
    float* out = (float*)d_out;

    char* ws = (char*)d_ws;
    u16*   Wq_b = (u16*)(ws);
    u16*   Wk_b = (u16*)(ws + 1179648L);
    u16*   Wv_b = (u16*)(ws + 2359296L);
    u16*   Wo_b = (u16*)(ws + 3538944L);
    u16*   Qb   = (u16*)(ws + 4718592L);
    u16*   Kb   = (u16*)(ws + 55050240L);
    u16*   Vb   = (u16*)(ws + 105381888L);
    float* P    = (float*)(ws + 155713536L);
    u16*   KVde = (u16*)(ws + 168296448L);
    u16*   W2t  = Kb;   // Kb dead after kv_partial2 — reuse

    dim3 blk(256);
    wconv<<<576, blk, 0, stream>>>(Wq, Wq_b, 589824);
    wconv<<<576, blk, 0, stream>>>(Wk, Wk_b, 589824);
    wconv<<<576, blk, 0, stream>>>(Wv, Wv_b, 589824);
    wconv<<<576, blk, 0, stream>>>(Wo, Wo_b, 589824);

    // 768 = 256 M-blocks x 3 N-blocks, XCD-swizzled inside the kernel
    gemm5<1, 1, 0, 0><<<768, blk, 0, stream>>>(q, Wq_b, bq, Qb);
    gemm5<1, 1, 0, 0><<<768, blk, 0, stream>>>(k, Wk_b, bk, Kb);
    gemm5<1, 0, 0, 0><<<768, blk, 0, stream>>>(v, Wv_b, bv, Vb);

    kv_partial2<<<dim3(48, 16), blk, 0, stream>>>(Kb, Vb, P);
    kv_reduce2<<<48, blk, 0, stream>>>(P, KVde);
    w2prep<<<dim3(3, 12, 4), blk, 0, stream>>>(Wo_b, KVde, W2t);

    gemm5<0, 0, 1, 1><<<768, blk, 0, stream>>>(Qb, W2t, bo, out);
}

// Round 14
// 304.035 us; speedup vs baseline: 1.2951x; 1.0858x over previous
//
#include <hip/hip_runtime.h>
#include <hip/hip_bf16.h>
#include <string.h>

// PerformerAttention: out = (relu(xWq^T+bq) @ [relu(xWk^T+bk)^T @ (xWv^T+bv)]_per-head) Wo^T + bo
// B=4 S=8192 E=768 H=12 Dh=64.
// Round 14: gemm6 = r13's 3-slot counted-vmcnt pipeline with
//  (1) cvt+ds_write of A moved AFTER the MFMA cluster (T14 write-late; regs get ~1 full
//      iter of latency cover; sched_barrier(0) pins order),
//  (2) all three projections merged into ONE 2304-block launch (z = input index) —
//      kills 2 inter-launch drains + cuts the 1.5-round tail waste 25%->11%.
// W2 fusion (r9) and XCD swizzle (r13) kept. Ledgers re-derived: steady vmcnt(8) AF32 /
// vmcnt(6) gload path; vmcnt(0) at last iter only.
//
// Workspace layout (bytes):
//   0        : Wq_b (1179648)   1179648: Wk_b   2359296: Wv_b   3538944: Wo_b
//              (Wq_b/Wk_b/Wv_b contiguous: stride 589824 u16 — merged kernel indexes by z)
//   4718592  : Qb   [32768,768] bf16 relu'd   (50331648)  \
//   55050240 : Kb   (reused as W2t after kv_partial2)      } stride 25165824 u16 by z
//   105381888: Vb                                         /
//   155713536: P    partial KVt [48*16][64e*64d] f32 (12582912)
//   168296448: KVde [48][64d*64e] bf16 (393216)

#define H_  12
#define DH  64
#define E_  768
#define S_  8192
#define B_  4

typedef unsigned short u16;
typedef __attribute__((ext_vector_type(4))) float f32x4;
typedef __attribute__((ext_vector_type(4))) u16   u16x4;
typedef __attribute__((ext_vector_type(8))) u16   u16x8;
typedef __attribute__((ext_vector_type(8))) short s16x8;

static __device__ __forceinline__ u16 f2bf(float f) {
    __hip_bfloat16 h = __float2bfloat16(f);
    u16 r; __builtin_memcpy(&r, &h, 2); return r;
}
static __device__ __forceinline__ float bf2f(u16 u) {
    unsigned int i = ((unsigned int)u) << 16;
    float f; __builtin_memcpy(&f, &i, 4); return f;
}

static __device__ __forceinline__ void gload16(const void* g, void* lds) {
    __builtin_amdgcn_global_load_lds(
        (const __attribute__((address_space(1))) unsigned int*)(uintptr_t)g,
        (__attribute__((address_space(3))) unsigned int*)(uintptr_t)lds,
        16, 0, 0);
}

// ---------------- weight f32 -> bf16 ----------------
__global__ __launch_bounds__(256) void wconv(const float* __restrict__ in,
                                             u16* __restrict__ out, int n) {
    int i = (blockIdx.x * 256 + threadIdx.x) * 4;
    if (i + 3 < n) {
        f32x4 v = *(const f32x4*)&in[i];
        u16x4 o;
        o[0] = f2bf(v[0]); o[1] = f2bf(v[1]); o[2] = f2bf(v[2]); o[3] = f2bf(v[3]);
        *(u16x4*)&out[i] = o;
    }
}

// ---------------- gemm6: XCD-swizzled deep-pipelined bf16 MFMA GEMM, NT ----------------
// BM=128, BN=256, BK=32, K=768, 4 waves (2Mx2N), wave tile 64x128, acc[4][8].
// LDS rows pack 2 logical rows per 128 B; swizzle bir ^= ((lrow&7)<<4) (verified, 0 confl).
// 3 slots, stage 2 tiles ahead, 1 s_barrier/tile.
// AF32: A reg-staged; loads issued at iter top (tile tt+2), cvt+ds_write AFTER the MFMA
// cluster (tile tt+1) — write-late so HBM latency hides under compute.
// MERGED: grid 2304; z = input {q,k,v}; relu for z<2.
template<int AF32, int OUT_F32, int PERB, int MERGED>
__global__ __launch_bounds__(256, 2) void gemm6(const void* __restrict__ A0,
                                                const void* __restrict__ A1,
                                                const void* __restrict__ A2,
                                                const u16* __restrict__ Bw0,
                                                const float* __restrict__ b0,
                                                const float* __restrict__ b1,
                                                const float* __restrict__ b2,
                                                void* __restrict__ C0) {
    constexpr int K = 768, NT = 24;
    __shared__ u16 As[3][4096];   // 3 x 8 KB
    __shared__ u16 Bs[3][8192];   // 3 x 16 KB
    const int t = threadIdx.x, lane = t & 63, wave = t >> 6;

    // XCD swizzle (HW: XCD = dispatch_index % 8): per XCD, inputs sequential,
    // the 3 N-sharers of each A-panel adjacent.
    const int phys = blockIdx.x;
    const int xcd  = phys & 7;
    const int idx  = phys >> 3;            // MERGED: 0..287, else 0..95
    int z, ii;
    if constexpr (MERGED) { z = idx / 96; ii = idx - z * 96; }
    else                  { z = 0;        ii = idx; }
    const int i3   = ii / 3;
    const int mblk = xcd * 32 + i3;        // 0..255
    const int nblk = ii - i3 * 3;          // 0..2
    const long m0  = (long)mblk * 128;
    const long n0  = (long)nblk * 256;
    const int  wr  = (wave >> 1) * 64;
    const int  wc  = (wave & 1) * 128;

    const void*  Ap   = MERGED ? (z == 0 ? A0 : (z == 1 ? A1 : A2)) : A0;
    const float* bias = MERGED ? (z == 0 ? b0 : (z == 1 ? b1 : b2)) : b0;
    const u16*   Bw   = PERB   ? (Bw0 + (long)(mblk >> 6) * 589824L)
                               : (MERGED ? (Bw0 + (long)z * 589824L) : Bw0);
    void*        Cp   = MERGED ? (void*)((u16*)C0 + (long)z * 25165824L) : C0;
    const int doRelu  = MERGED ? (z < 2) : 0;

    // ---- B staging: 16 chunks of 1 KB, 4/wave; involuted source (verified) ----
    const u16* srcB[4]; int dstB[4];
    #pragma unroll
    for (int c = 0; c < 4; ++c) {
        int ch   = wave * 4 + c;
        int o    = ch * 1024 + lane * 16;
        int lrow = o >> 7;
        int bir  = (o & 127) ^ ((lrow & 7) << 4);
        int row  = 2 * lrow + (bir >> 6);
        dstB[c]  = ch * 1024;
        srcB[c]  = Bw + (n0 + row) * (long)K + ((bir & 63) >> 1);
    }
    // ---- A staging descriptors ----
    const u16*   srcA[2]; int dstA[2];                    // AF32 == 0
    const float* aptr = nullptr; int awr0 = 0, awr1 = 0;  // AF32 == 1
    if constexpr (AF32) {
        const int ar = t >> 1;             // logical row 0..127
        const int ac = (t & 1) * 16;       // f32 col
        aptr = (const float*)Ap + (m0 + ar) * (long)K + ac;
        const int lrow = ar >> 1;
        const int kb0  = (t & 1) * 32;
        awr0 = lrow * 128 + ((((ar & 1) << 6) | (kb0))       ^ ((lrow & 7) << 4));
        awr1 = lrow * 128 + ((((ar & 1) << 6) | (kb0 + 16))  ^ ((lrow & 7) << 4));
    } else {
        #pragma unroll
        for (int c = 0; c < 2; ++c) {
            int ch   = wave * 2 + c;
            int o    = ch * 1024 + lane * 16;
            int lrow = o >> 7;
            int bir  = (o & 127) ^ ((lrow & 7) << 4);
            int row  = 2 * lrow + (bir >> 6);
            dstA[c]  = ch * 1024;
            srcA[c]  = (const u16*)Ap + (m0 + row) * (long)K + ((bir & 63) >> 1);
        }
    }

    // ---- swizzled frag-read byte offsets (verified layout) ----
    const int kg16 = (lane >> 4) * 16;
    int aoff[4], boff[8];
    #pragma unroll
    for (int mi = 0; mi < 4; ++mi) {
        int m    = wr + mi * 16 + (lane & 15);
        int lrow = m >> 1;
        aoff[mi] = lrow * 128 + ((((m & 1) << 6) | kg16) ^ ((lrow & 7) << 4));
    }
    #pragma unroll
    for (int ni = 0; ni < 8; ++ni) {
        int n    = wc + ni * 16 + (lane & 15);
        int lrow = n >> 1;
        boff[ni] = lrow * 128 + ((((n & 1) << 6) | kg16) ^ ((lrow & 7) << 4));
    }

    f32x4 acc[4][8] = {};
    f32x4 ra[2][4];   // A(n) in ra[n&1]; full unroll -> static parity

    // ---- prologue ----
    if constexpr (AF32) {
        #pragma unroll
        for (int j = 0; j < 4; ++j) ra[0][j] = *(const f32x4*)(aptr + j * 4);          // A(0)
        #pragma unroll
        for (int c = 0; c < 4; ++c) gload16(srcB[c], (char*)&Bs[0][0] + dstB[c]);      // B(0)
        {   // cvt + write A(0) -> slot 0 (one-time stall, fine)
            u16x8 o8;
            #pragma unroll
            for (int x = 0; x < 4; ++x) { o8[x] = f2bf(ra[0][0][x]); o8[x + 4] = f2bf(ra[0][1][x]); }
            *(u16x8*)((char*)&As[0][0] + awr0) = o8;
            #pragma unroll
            for (int x = 0; x < 4; ++x) { o8[x] = f2bf(ra[0][2][x]); o8[x + 4] = f2bf(ra[0][3][x]); }
            *(u16x8*)((char*)&As[0][0] + awr1) = o8;
        }
        #pragma unroll
        for (int j = 0; j < 4; ++j) ra[1][j] = *(const f32x4*)(aptr + 32 + j * 4);     // A(1)
        #pragma unroll
        for (int c = 0; c < 4; ++c) gload16(srcB[c] + 32, (char*)&Bs[1][0] + dstB[c]); // B(1)
    } else {
        #pragma unroll
        for (int c = 0; c < 2; ++c) gload16(srcA[c],      (char*)&As[0][0] + dstA[c]);
        #pragma unroll
        for (int c = 0; c < 4; ++c) gload16(srcB[c],      (char*)&Bs[0][0] + dstB[c]);
        #pragma unroll
        for (int c = 0; c < 2; ++c) gload16(srcA[c] + 32, (char*)&As[1][0] + dstA[c]);
        #pragma unroll
        for (int c = 0; c < 4; ++c) gload16(srcB[c] + 32, (char*)&Bs[1][0] + dstB[c]);
    }

    // ---- main loop (fully unrolled) ----
    #pragma unroll
    for (int tt = 0; tt < NT; ++tt) {
        asm volatile("s_waitcnt lgkmcnt(0)" ::: "memory");
        // Ledger: need B(tt) (and A(tt) for !AF32) landed; newer = iter tt-1's issues.
        if (tt < NT - 1) {
            if constexpr (AF32) asm volatile("s_waitcnt vmcnt(8)" ::: "memory");
            else                asm volatile("s_waitcnt vmcnt(6)" ::: "memory");
        } else {
            asm volatile("s_waitcnt vmcnt(0)" ::: "memory");
        }
        asm volatile("s_barrier" ::: "memory");

        const int sl = tt % 3;
        if (tt + 2 < NT) {
            const int isl = (tt + 2) % 3;
            const int k0  = (tt + 2) * 32;
            if constexpr (AF32) {
                #pragma unroll
                for (int j = 0; j < 4; ++j) ra[tt & 1][j] = *(const f32x4*)(aptr + k0 + j * 4);
            } else {
                #pragma unroll
                for (int c = 0; c < 2; ++c) gload16(srcA[c] + k0, (char*)&As[isl][0] + dstA[c]);
            }
            #pragma unroll
            for (int c = 0; c < 4; ++c) gload16(srcB[c] + k0, (char*)&Bs[isl][0] + dstB[c]);
        }

        const char* as = (const char*)&As[sl][0];
        const char* bs = (const char*)&Bs[sl][0];
        s16x8 af[4], bf[8];
        #pragma unroll
        for (int mi = 0; mi < 4; ++mi) af[mi] = *(const s16x8*)(as + aoff[mi]);
        #pragma unroll
        for (int ni = 0; ni < 8; ++ni) bf[ni] = *(const s16x8*)(bs + boff[ni]);

        __builtin_amdgcn_s_setprio(1);
        #pragma unroll
        for (int mi = 0; mi < 4; ++mi)
            #pragma unroll
            for (int ni = 0; ni < 8; ++ni)
                acc[mi][ni] = __builtin_amdgcn_mfma_f32_16x16x32_bf16(af[mi], bf[ni], acc[mi][ni], 0, 0, 0);
        __builtin_amdgcn_s_setprio(0);

        if constexpr (AF32) {
            // write-late: cvt + ds_write A(tt+1) AFTER the MFMA cluster (T14).
            // sched_barrier keeps the compiler from hoisting it back before the MFMAs.
            __builtin_amdgcn_sched_barrier(0);
            if (tt + 1 < NT) {
                const int wsl = (tt + 1) % 3;
                const f32x4* rv = ra[(tt + 1) & 1];
                u16x8 o8;
                #pragma unroll
                for (int x = 0; x < 4; ++x) { o8[x] = f2bf(rv[0][x]); o8[x + 4] = f2bf(rv[1][x]); }
                *(u16x8*)((char*)&As[wsl][0] + awr0) = o8;
                #pragma unroll
                for (int x = 0; x < 4; ++x) { o8[x] = f2bf(rv[2][x]); o8[x + 4] = f2bf(rv[3][x]); }
                *(u16x8*)((char*)&As[wsl][0] + awr1) = o8;
            }
        }
    }

    // ---- epilogue: C/D layout col = lane&15, row = (lane>>4)*4 + r (verified) ----
    const int cc = lane & 15;
    const int cr = (lane >> 4) * 4;
    float bv[8];
    #pragma unroll
    for (int ni = 0; ni < 8; ++ni) bv[ni] = bias[n0 + wc + ni * 16 + cc];
    #pragma unroll
    for (int mi = 0; mi < 4; ++mi) {
        #pragma unroll
        for (int r = 0; r < 4; ++r) {
            long gm = m0 + wr + mi * 16 + cr + r;
            #pragma unroll
            for (int ni = 0; ni < 8; ++ni) {
                long gn = n0 + wc + ni * 16 + cc;
                float v = acc[mi][ni][r] + bv[ni];
                if (doRelu) v = fmaxf(v, 0.0f);
                if (OUT_F32) ((float*)Cp)[gm * 768 + gn] = v;
                else         ((u16*)Cp)[gm * 768 + gn]   = f2bf(v);
            }
        }
    }
}

// ---------------- KV partial v2 (verified): P[bhc][e][d] = sum_l V[l,e]*K[l,d] -------
__global__ __launch_bounds__(256) void kv_partial2(const u16* __restrict__ Kb,
                                                   const u16* __restrict__ Vb,
                                                   float* __restrict__ P) {
    __shared__ float sbuf[8192];
    const int bh = blockIdx.x, ch = blockIdx.y;
    const int b = bh / H_, h = bh - b * H_;
    const int t = threadIdx.x, lane = t & 63, wave = t >> 6;
    float* Kf = sbuf + wave * 2048;
    float* Vf = Kf + 1024;
    const long base = ((long)b * S_) * E_ + h * DH;
    const int eB = (lane >> 3) * 8;
    const int dB = (lane & 7) * 8;

    f32x4 acc[8][2] = {};

    const int l0w = ch * 512 + wave * 128;
    for (int ss = 0; ss < 8; ++ss) {
        const int l0 = l0w + ss * 16;
        #pragma unroll
        for (int half = 0; half < 2; ++half) {
            int u  = lane + half * 64;
            int lr = u >> 3, c0 = (u & 7) * 8;
            long g = base + (long)(l0 + lr) * E_ + c0;
            u16x8 kk = *(const u16x8*)&Kb[g];
            u16x8 vv = *(const u16x8*)&Vb[g];
            f32x4 k0, k1, v0, v1;
            #pragma unroll
            for (int j = 0; j < 4; ++j) {
                k0[j] = bf2f(kk[j]); k1[j] = bf2f(kk[j + 4]);
                v0[j] = bf2f(vv[j]); v1[j] = bf2f(vv[j + 4]);
            }
            *(f32x4*)&Kf[lr * 64 + c0]     = k0;
            *(f32x4*)&Kf[lr * 64 + c0 + 4] = k1;
            *(f32x4*)&Vf[lr * 64 + c0]     = v0;
            *(f32x4*)&Vf[lr * 64 + c0 + 4] = v1;
        }
        #pragma unroll
        for (int l = 0; l < 16; ++l) {
            f32x4 e0 = *(const f32x4*)&Vf[l * 64 + eB];
            f32x4 e1 = *(const f32x4*)&Vf[l * 64 + eB + 4];
            f32x4 d0 = *(const f32x4*)&Kf[l * 64 + dB];
            f32x4 d1 = *(const f32x4*)&Kf[l * 64 + dB + 4];
            #pragma unroll
            for (int i = 0; i < 4; ++i) {
                acc[i][0]     += e0[i] * d0;  acc[i][1]     += e0[i] * d1;
                acc[i + 4][0] += e1[i] * d0;  acc[i + 4][1] += e1[i] * d1;
            }
        }
    }

    __syncthreads();
    if (wave >= 2) {
        float* r = sbuf + (wave - 2) * 4096;
        #pragma unroll
        for (int i = 0; i < 8; ++i) {
            *(f32x4*)&r[(eB + i) * 64 + dB]     = acc[i][0];
            *(f32x4*)&r[(eB + i) * 64 + dB + 4] = acc[i][1];
        }
    }
    __syncthreads();
    if (wave < 2) {
        const float* r = sbuf + wave * 4096;
        #pragma unroll
        for (int i = 0; i < 8; ++i) {
            acc[i][0] += *(const f32x4*)&r[(eB + i) * 64 + dB];
            acc[i][1] += *(const f32x4*)&r[(eB + i) * 64 + dB + 4];
        }
    }
    __syncthreads();
    if (wave == 1) {
        #pragma unroll
        for (int i = 0; i < 8; ++i) {
            *(f32x4*)&sbuf[(eB + i) * 64 + dB]     = acc[i][0];
            *(f32x4*)&sbuf[(eB + i) * 64 + dB + 4] = acc[i][1];
        }
    }
    __syncthreads();
    if (wave == 0) {
        float* Pp = &P[((long)(bh * 16 + ch)) * 4096];
        #pragma unroll
        for (int i = 0; i < 8; ++i) {
            f32x4 s0 = acc[i][0] + *(const f32x4*)&sbuf[(eB + i) * 64 + dB];
            f32x4 s1 = acc[i][1] + *(const f32x4*)&sbuf[(eB + i) * 64 + dB + 4];
            *(f32x4*)&Pp[(eB + i) * 64 + dB]     = s0;
            *(f32x4*)&Pp[(eB + i) * 64 + dB + 4] = s1;
        }
    }
}

// ---------------- KV reduce (transposing): KVde[bh][d*64+e] bf16 ----------------
__global__ __launch_bounds__(256) void kv_reduce2(const float* __restrict__ P,
                                                  u16* __restrict__ KVde) {
    const int bh = blockIdx.x, t = threadIdx.x;
    #pragma unroll
    for (int k = 0; k < 4; ++k) {
        int i = t * 4 + k * 1024;
        f32x4 s = {};
        for (int c = 0; c < 16; ++c) s += *(const f32x4*)&P[((long)(bh * 16 + c)) * 4096 + i];
        const int e = i >> 6, d0 = i & 63;
        #pragma unroll
        for (int j = 0; j < 4; ++j)
            KVde[(long)bh * 4096 + (d0 + j) * 64 + e] = f2bf(s[j]);
    }
}

// ---------------- w2prep (verified): W2t[b][n][(h,d)] = sum_e Wo[n][(h,e)]*KVde[b,h][d][e]
__global__ __launch_bounds__(256) void w2prep(const u16* __restrict__ Wo_b,
                                              const u16* __restrict__ KVde,
                                              u16* __restrict__ W2t) {
    __shared__ u16 Qs[256 * 64];
    __shared__ u16 Ks[64 * 64];
    const int t = threadIdx.x, lane = t & 63, wave = t >> 6;
    const int h = blockIdx.y, b = blockIdx.z;
    const int n0 = blockIdx.x * 256;

    {
        char* lq = (char*)Qs;
        #pragma unroll
        for (int j = 0; j < 8; ++j) {
            int ob = (wave * 8 + j) * 1024;
            int ol = ob + lane * 16;
            int row = ol >> 7, col = (ol & 127) >> 1;
            gload16(&Wo_b[(long)(n0 + row) * E_ + h * DH + col], lq + ob);
        }
        char* lk = (char*)Ks;
        #pragma unroll
        for (int j = 0; j < 2; ++j) {
            int ob = (wave * 2 + j) * 1024;
            int ol = ob + lane * 16;
            int row = ol >> 7, col = (ol & 127) >> 1;
            gload16(&KVde[((long)(b * H_ + h)) * 4096 + row * 64 + col], lk + ob);
        }
    }
    __syncthreads();

    f32x4 acc[4][4] = {};
    #pragma unroll
    for (int kk = 0; kk < 2; ++kk) {
        s16x8 af[4], bfr[4];
        #pragma unroll
        for (int mi = 0; mi < 4; ++mi)
            af[mi] = *(const s16x8*)&Qs[(wave * 64 + mi * 16 + (lane & 15)) * 64 + kk * 32 + (lane >> 4) * 8];
        #pragma unroll
        for (int ni = 0; ni < 4; ++ni)
            bfr[ni] = *(const s16x8*)&Ks[(ni * 16 + (lane & 15)) * 64 + kk * 32 + (lane >> 4) * 8];
        #pragma unroll
        for (int mi = 0; mi < 4; ++mi)
            #pragma unroll
            for (int ni = 0; ni < 4; ++ni)
                acc[mi][ni] = __builtin_amdgcn_mfma_f32_16x16x32_bf16(af[mi], bfr[ni], acc[mi][ni], 0, 0, 0);
    }

    const int cc = lane & 15, cr = (lane >> 4) * 4;
    u16* Wb = W2t + (long)b * 589824L;
    #pragma unroll
    for (int mi = 0; mi < 4; ++mi) {
        #pragma unroll
        for (int r = 0; r < 4; ++r) {
            long gm = n0 + wave * 64 + mi * 16 + cr + r;
            #pragma unroll
            for (int ni = 0; ni < 4; ++ni)
                Wb[gm * E_ + h * DH + ni * 16 + cc] = f2bf(acc[mi][ni][r]);
        }
    }
}

extern "C" void kernel_launch(void* const* d_in, const int* in_sizes, int n_in,
                              void* d_out, int out_size, void* d_ws, size_t ws_size,
                              hipStream_t stream) {
    const float* q  = (const float*)d_in[0];
    const float* k  = (const float*)d_in[1];
    const float* v  = (const float*)d_in[2];
    const float* Wq = (const float*)d_in[3];
    const float* bq = (const float*)d_in[4];
    const float* Wk = (const float*)d_in[5];
    const float* bk = (const float*)d_in[6];
    const float* Wv = (const float*)d_in[7];
    const float* bv = (const float*)d_in[8];
    const float* Wo = (const float*)d_in[9];
    const float* bo = (const float*)d_in[10];
    float* out = (float*)d_out;

    char* ws = (char*)d_ws;
    u16*   Wq_b = (u16*)(ws);                 // Wq_b/Wk_b/Wv_b contiguous (stride 589824 u16)
    u16*   Wk_b = (u16*)(ws + 1179648L);
    u16*   Wv_b = (u16*)(ws + 2359296L);
    u16*   Wo_b = (u16*)(ws + 3538944L);
    u16*   Qb   = (u16*)(ws + 4718592L);      // Qb/Kb/Vb contiguous (stride 25165824 u16)
    u16*   Kb   = (u16*)(ws + 55050240L);
    u16*   Vb   = (u16*)(ws + 105381888L);
    float* P    = (float*)(ws + 155713536L);
    u16*   KVde = (u16*)(ws + 168296448L);
    u16*   W2t  = Kb;   // Kb dead after kv_partial2 — reuse

    dim3 blk(256);
    wconv<<<576, blk, 0, stream>>>(Wq, Wq_b, 589824);
    wconv<<<576, blk, 0, stream>>>(Wk, Wk_b, 589824);
    wconv<<<576, blk, 0, stream>>>(Wv, Wv_b, 589824);
    wconv<<<576, blk, 0, stream>>>(Wo, Wo_b, 589824);

    // merged projections: 2304 blocks = 3 inputs x (256 M-blocks x 3 N-blocks)
    gemm6<1, 0, 0, 1><<<2304, blk, 0, stream>>>(q, k, v, Wq_b, bq, bk, bv, Qb);

    kv_partial2<<<dim3(48, 16), blk, 0, stream>>>(Kb, Vb, P);
    kv_reduce2<<<48, blk, 0, stream>>>(P, KVde);
    w2prep<<<dim3(3, 12, 4), blk, 0, stream>>>(Wo_b, KVde, W2t);

    // final: out = Qb @ W2t[b]^T + bo
    gemm6<0, 1, 1, 0><<<768, blk, 0, stream>>>(Qb, nullptr, nullptr, W2t, bo, nullptr, nullptr, out);
}